// Round 20
// baseline (162.056 us; speedup 1.0000x reference)
//
#include <hip/hip_runtime.h>
#include <math.h>

#define NH 4
#define NF 64
#define NM 32
#define NT 16  // nodes per block in k_projm
#define SC 32  // elements per thread in k_scan (supports N <= 32768)
#define AW 8   // waves per block in k_aggout

typedef __attribute__((ext_vector_type(8))) short bf16x8;
typedef __attribute__((ext_vector_type(4))) float f32x4;

// fast transcendentals (hardware v_exp/v_log/v_rcp); absmax margin 0.03 vs 0.105 absorbs ~1e-6
__device__ __forceinline__ float fexp(float v){ return __expf(v); }
__device__ __forceinline__ float softplusf(float v){ return fmaxf(v, 0.f) + __logf(1.f + __expf(-fabsf(v))); }
__device__ __forceinline__ float sigmoidf_(float v){ return __fdividef(1.f, 1.f + __expf(-v)); }
__device__ __forceinline__ unsigned short f2bf(float f) {
  unsigned u = __float_as_uint(f);
  u = u + 0x7FFFu + ((u >> 16) & 1u);   // round-to-nearest-even
  return (unsigned short)(u >> 16);
}
__device__ __forceinline__ float bflo(unsigned u){ return __uint_as_float(u << 16); }
__device__ __forceinline__ float bfhi(unsigned u){ return __uint_as_float(u & 0xFFFF0000u); }

// ---------------- K0: pack weights into MFMA fragments + zero deg/cursor ----------------
__global__ void k_pack(const float* __restrict__ Wp, const float* __restrict__ Wr,
                       const float* __restrict__ Wt,
                       const float* __restrict__ dW1, const float* __restrict__ tW1,
                       unsigned short* __restrict__ Wpk, int* __restrict__ z, int nz) {
  int t = blockIdx.x * blockDim.x + threadIdx.x;   // 8192 threads
  // grid-stride zero of deg+cursor
  for (int i = t; i < nz; i += 8192) z[i] = 0;
  int lane = t & 63;
  int frag = t >> 6;   // 0..127
  if (frag >= 128) return;
  if (frag < 96) {
    int nb = frag & 3, kb = (frag >> 2) & 1, h = (frag >> 3) & 3, q = frag >> 5;
    const float* W = (q == 0 ? Wp : (q == 1 ? Wr : Wt));
    int col = nb * 16 + (lane & 15);
    int krow = kb * 32 + (lane >> 4) * 8;
    #pragma unroll
    for (int j = 0; j < 8; ++j)
      Wpk[((size_t)frag * 64 + lane) * 8 + j] = f2bf(W[(size_t)h * NF * NF + (krow + j) * NF + col]);
  } else {
    int f2 = frag - 96;
    int nb = f2 & 1, kb = (f2 >> 1) & 1, h = (f2 >> 2) & 3, p2 = f2 >> 4;
    const float* W = (p2 == 0 ? dW1 : tW1);
    int col = nb * 16 + (lane & 15);
    int krow = kb * 32 + (lane >> 4) * 8;
    #pragma unroll
    for (int j = 0; j < 8; ++j)
      Wpk[((size_t)frag * 64 + lane) * 8 + j] = f2bf(W[(size_t)h * NF * NM + (krow + j) * NM + col]);
  }
}

// ---------------- K0b: degree count ----------------
__global__ void k_count(const int* __restrict__ ei, int* __restrict__ deg, int E) {
  int e = blockIdx.x * blockDim.x + threadIdx.x;
  if (e < E) atomicAdd(&deg[ei[E + e]], 1);
}

// ---------------- K1: MFMA node pass (pt stored bf16) ----------------
__global__ __launch_bounds__(256)
void k_projm(const float* __restrict__ x, const unsigned short* __restrict__ Wpk,
             const float* __restrict__ rsc, const float* __restrict__ tsc,
             const float* __restrict__ db1, const float* __restrict__ dw2, const float* __restrict__ db2,
             const float* __restrict__ tb1, const float* __restrict__ tw2, const float* __restrict__ tb2,
             const float* __restrict__ rdls, const float* __restrict__ rtb,
             unsigned short* __restrict__ ptb, float* __restrict__ sr, float* __restrict__ st,
             float* __restrict__ doff, float* __restrict__ toff, int N) {
  int n0 = blockIdx.x * NT;
  int tid = threadIdx.x;
  int h = tid >> 6, l = tid & 63;
  int lo = l & 15, hi = l >> 4;
  __shared__ __align__(16) unsigned short eps16[NH][16][72];  // bf16 ep, padded rows (144B)

  const bf16x8* W8 = (const bf16x8*)Wpk;

  // A fragments from x: lane l = row (n0+lo), k = kb*32 + hi*8 + j
  bf16x8 a[2];
  {
    int nr = n0 + lo; if (nr >= N) nr = N - 1;
    const float* xr = x + (size_t)nr * NF + hi * 8;
    #pragma unroll
    for (int kb = 0; kb < 2; ++kb) {
      float4 v0 = *(const float4*)(xr + kb * 32);
      float4 v1 = *(const float4*)(xr + kb * 32 + 4);
      bf16x8 aa;
      aa[0] = (short)f2bf(v0.x); aa[1] = (short)f2bf(v0.y);
      aa[2] = (short)f2bf(v0.z); aa[3] = (short)f2bf(v0.w);
      aa[4] = (short)f2bf(v1.x); aa[5] = (short)f2bf(v1.y);
      aa[6] = (short)f2bf(v1.z); aa[7] = (short)f2bf(v1.w);
      a[kb] = aa;
    }
  }

  float srp[4] = {0.f,0.f,0.f,0.f}, stp[4] = {0.f,0.f,0.f,0.f};
  // ---- projection GEMMs ----
  #pragma unroll
  for (int q = 0; q < 3; ++q) {
    #pragma unroll
    for (int nb = 0; nb < 4; ++nb) {
      f32x4 c = {0.f, 0.f, 0.f, 0.f};
      #pragma unroll
      for (int kb = 0; kb < 2; ++kb) {
        int frag = ((q * 4 + h) * 2 + kb) * 4 + nb;
        c = __builtin_amdgcn_mfma_f32_16x16x32_bf16(a[kb], W8[frag * 64 + l], c, 0, 0, 0);
      }
      int g = nb * 16 + lo;
      if (q == 0) {
        float rs = rsc[h * NF + g], ts = tsc[h * NF + g];
        #pragma unroll
        for (int r = 0; r < 4; ++r) {
          eps16[h][hi * 4 + r][g] = f2bf(c[r]);
          srp[r] += c[r] * rs;
          stp[r] += c[r] * ts;
        }
      } else {
        int row = (q - 1) * NH + h;
        #pragma unroll
        for (int r = 0; r < 4; ++r) {
          int n = n0 + hi * 4 + r;
          if (n < N) ptb[((size_t)n * NF + g) * 8 + row] = f2bf(c[r]);
        }
      }
    }
  }
  // reduce sr/st over the 16-lane column group
  #pragma unroll
  for (int off = 1; off < 16; off <<= 1)
    #pragma unroll
    for (int r = 0; r < 4; ++r) { srp[r] += __shfl_xor(srp[r], off); stp[r] += __shfl_xor(stp[r], off); }
  if (lo == 0) {
    #pragma unroll
    for (int r = 0; r < 4; ++r) {
      int n = n0 + hi * 4 + r;
      if (n < N) { sr[n * NH + h] = srp[r]; st[n * NH + h] = stp[r]; }
    }
  }

  // ---- MLPs (A = ep bf16 from wave-local LDS) ----
  asm volatile("s_waitcnt lgkmcnt(0)" ::: "memory");
  bf16x8 ea[2];
  #pragma unroll
  for (int kb = 0; kb < 2; ++kb)
    ea[kb] = *(const bf16x8*)&eps16[h][lo][kb * 32 + hi * 8];

  float dpp[4] = {0.f,0.f,0.f,0.f}, tpp[4] = {0.f,0.f,0.f,0.f};
  #pragma unroll
  for (int p2 = 0; p2 < 2; ++p2) {
    #pragma unroll
    for (int nb = 0; nb < 2; ++nb) {
      f32x4 c = {0.f, 0.f, 0.f, 0.f};
      #pragma unroll
      for (int kb = 0; kb < 2; ++kb) {
        int frag = 96 + ((p2 * 4 + h) * 2 + kb) * 2 + nb;
        c = __builtin_amdgcn_mfma_f32_16x16x32_bf16(ea[kb], W8[frag * 64 + l], c, 0, 0, 0);
      }
      int m = nb * 16 + lo;
      float b1 = (p2 == 0 ? db1 : tb1)[h * NM + m];
      float w2 = (p2 == 0 ? dw2 : tw2)[h * NM + m];
      #pragma unroll
      for (int r = 0; r < 4; ++r) {
        float av = c[r] + b1;
        float sv = av * sigmoidf_(av) * w2;   // silu * w2
        if (p2 == 0) dpp[r] += sv; else tpp[r] += sv;
      }
    }
  }
  #pragma unroll
  for (int off = 1; off < 16; off <<= 1)
    #pragma unroll
    for (int r = 0; r < 4; ++r) { dpp[r] += __shfl_xor(dpp[r], off); tpp[r] += __shfl_xor(tpp[r], off); }
  if (lo == 0) {
    float dbase = db2[h] + softplusf(rdls[h]);
    float tbase = tb2[h] + rtb[h];
    #pragma unroll
    for (int r = 0; r < 4; ++r) {
      int n = n0 + hi * 4 + r;
      if (n < N) { doff[n * NH + h] = dpp[r] + dbase; toff[n * NH + h] = tpp[r] + tbase; }
    }
  }
}

// ---------------- K2: exclusive prefix scan (thread-serial + one tree) ----------------
__global__ void k_scan(const int* __restrict__ deg, int* __restrict__ start, int N) {
  __shared__ int sums[1024];
  int tid = threadIdx.x;
  int base = tid * SC;
  int local[SC];
  int s = 0;
  #pragma unroll
  for (int j = 0; j < SC; ++j) {
    int i = base + j;
    int v = (i < N) ? deg[i] : 0;
    local[j] = s;   // exclusive local prefix
    s += v;
  }
  sums[tid] = s;
  __syncthreads();
  for (int off = 1; off < 1024; off <<= 1) {
    int t = (tid >= off) ? sums[tid - off] : 0;
    __syncthreads();
    sums[tid] += t;
    __syncthreads();
  }
  int tbase = (tid > 0) ? sums[tid - 1] : 0;
  #pragma unroll
  for (int j = 0; j < SC; ++j) {
    int i = base + j;
    if (i < N) start[i] = tbase + local[j];
  }
  if (tid == 1023) start[N] = sums[1023];
}

// ---------------- K3: CSR fill (snd + elen only) ----------------
__global__ void k_fill(const int* __restrict__ ei, const float* __restrict__ elen,
                       const int* __restrict__ start, int* __restrict__ cursor,
                       int* __restrict__ csnd, float* __restrict__ celen, int E) {
  int e = blockIdx.x * blockDim.x + threadIdx.x;
  if (e >= E) return;
  int r = ei[E + e];
  int slot = start[r] + atomicAdd(&cursor[r], 1);
  csnd[slot] = ei[e];
  celen[slot] = elen[e];
}

// ---------------- K4: fused logits + softmax + gather-aggregate + Wout + residual ----------------
// coef_s transposed [8][64]: writes conflict-free, reads uniform broadcast (stride 64)
__device__ __forceinline__ float dot8t(const float* cf, uint4 uv) {
  return cf[0*64] * bflo(uv.x) + cf[1*64] * bfhi(uv.x)
       + cf[2*64] * bflo(uv.y) + cf[3*64] * bfhi(uv.y)
       + cf[4*64] * bflo(uv.z) + cf[5*64] * bfhi(uv.z)
       + cf[6*64] * bflo(uv.w) + cf[7*64] * bfhi(uv.w);
}

__global__ __launch_bounds__(512)
void k_aggout(const int* __restrict__ start, const int* __restrict__ csnd, const float* __restrict__ celen,
              const float4* __restrict__ sr4, const float4* __restrict__ st4,
              const float4* __restrict__ doff4, const float4* __restrict__ toff4,
              const float* __restrict__ rtw, const float* __restrict__ mixb, const float* __restrict__ mixs,
              const unsigned short* __restrict__ ptb, const float* __restrict__ x,
              const float* __restrict__ Wout, float* __restrict__ out, int N) {
  __shared__ float wout_s[NF * NF];
  __shared__ float coef_s[AW][8][64];
  __shared__ int   snd_s[AW][64];
  __shared__ float am_s[AW][NF];
  int tid = threadIdx.x;
  {
    const float4* w4 = (const float4*)Wout;
    float4* s4 = (float4*)wout_s;
    for (int i = tid; i < NF * NF / 4; i += 512) s4[i] = w4[i];
  }
  __syncthreads();   // only block-wide barrier; everything after is wave-local
  int w = tid >> 6, g = tid & 63;
  int n = blockIdx.x * AW + w;
  if (n >= N) return;
  int i0 = start[n], i1 = start[n + 1];
  int deg = i1 - i0;

  // receiver-side broadcast values
  float4 srn = sr4[n], stn = st4[n], dofn = doff4[n], tofn = toff4[n];
  const float* srnp = (const float*)&srn; const float* stnp = (const float*)&stn;
  const float* dofnp = (const float*)&dofn; const float* tofnp = (const float*)&tofn;
  float rtwv[NH], mbv[NH], msv[NH];
  #pragma unroll
  for (int h = 0; h < NH; ++h) { rtwv[h] = rtw[h]; mbv[h] = mixb[h]; msv[h] = mixs[h]; }

  float rm[NH], tm[NH];
  float rs_[NH] = {0.f,0.f,0.f,0.f}, ts_[NH] = {0.f,0.f,0.f,0.f};
  float sc1[NH] = {0.f,0.f,0.f,0.f}, sc2[NH] = {0.f,0.f,0.f,0.f};
  float acc0 = 0.f, acc1 = 0.f, acc2 = 0.f, acc3 = 0.f;

  if (deg <= 64) {
    // ---------- fast path: lane = edge, logits live in registers ----------
    int i = i0 + g;
    bool act = (i < i1);
    int s = act ? csnd[i] : 0;
    float len = act ? celen[i] : 0.f;
    float4 as4 = sr4[s], cs4 = st4[s];
    const float* asp = (const float*)&as4; const float* csp = (const float*)&cs4;
    float rlv[NH], tlv[NH], gvv[NH];
    #pragma unroll
    for (int h = 0; h < NH; ++h) {
      float temp = softplusf(tofnp[h] + rtwv[h] * len);
      rlv[h] = act ? __fdividef(asp[h] - srnp[h] - dofnp[h] * len, temp + 1e-4f) : -1e30f;
      tlv[h] = act ? (csp[h] - stnp[h]) : -1e30f;
      gvv[h] = sigmoidf_(mbv[h] + msv[h] * len);
      rm[h] = rlv[h]; tm[h] = tlv[h];
    }
    #pragma unroll
    for (int off = 32; off; off >>= 1)
      #pragma unroll
      for (int h = 0; h < NH; ++h) {
        rm[h] = fmaxf(rm[h], __shfl_xor(rm[h], off));
        tm[h] = fmaxf(tm[h], __shfl_xor(tm[h], off));
      }
    float er[NH], et[NH];
    #pragma unroll
    for (int h = 0; h < NH; ++h) {
      er[h] = act ? fexp(rlv[h] - rm[h]) : 0.f;
      et[h] = act ? fexp(tlv[h] - tm[h]) : 0.f;
      rs_[h] = er[h]; ts_[h] = et[h];
    }
    #pragma unroll
    for (int off = 32; off; off >>= 1)
      #pragma unroll
      for (int h = 0; h < NH; ++h) { rs_[h] += __shfl_xor(rs_[h], off); ts_[h] += __shfl_xor(ts_[h], off); }
    #pragma unroll
    for (int h = 0; h < NH; ++h) { rs_[h] = __fdividef(1.f, rs_[h] + 1e-9f); ts_[h] = __fdividef(1.f, ts_[h] + 1e-9f); }
    #pragma unroll
    for (int h = 0; h < NH; ++h) {
      float ar = er[h] * rs_[h];
      float at = et[h] * ts_[h];
      float gg = gvv[h];
      float ba = gg * ar + (1.f - gg) * at;
      float c1 = ba * gg, c2 = ba * (1.f - gg);
      coef_s[w][h][g] = c1; coef_s[w][4 + h][g] = c2;
      sc1[h] = c1; sc2[h] = c2;   // inactive lanes: er=et=0 -> c1=c2=0
    }
    snd_s[w][g] = s;
    // gather (lane = feature, 4-way ILP)
    int j = 0;
    for (; j + 4 <= deg; j += 4) {
      uint4 u0 = *(const uint4*)(ptb + ((size_t)snd_s[w][j]     * NF + g) * 8);
      uint4 u1 = *(const uint4*)(ptb + ((size_t)snd_s[w][j + 1] * NF + g) * 8);
      uint4 u2 = *(const uint4*)(ptb + ((size_t)snd_s[w][j + 2] * NF + g) * 8);
      uint4 u3 = *(const uint4*)(ptb + ((size_t)snd_s[w][j + 3] * NF + g) * 8);
      acc0 += dot8t(&coef_s[w][0][j],     u0);
      acc1 += dot8t(&coef_s[w][0][j + 1], u1);
      acc2 += dot8t(&coef_s[w][0][j + 2], u2);
      acc3 += dot8t(&coef_s[w][0][j + 3], u3);
    }
    for (; j < deg; ++j) {
      uint4 u0 = *(const uint4*)(ptb + ((size_t)snd_s[w][j] * NF + g) * 8);
      acc0 += dot8t(&coef_s[w][0][j], u0);
    }
  } else {
    // ---------- slow path (deg > 64): chunked 3 passes, logits recomputed ----------
    #pragma unroll
    for (int h = 0; h < NH; ++h) { rm[h] = -1e30f; tm[h] = -1e30f; }
    for (int base = i0; base < i1; base += 64) {
      int i = base + g; bool act = (i < i1);
      int s = act ? csnd[i] : 0; float len = act ? celen[i] : 0.f;
      float4 as4 = sr4[s], cs4 = st4[s];
      const float* asp = (const float*)&as4; const float* csp = (const float*)&cs4;
      #pragma unroll
      for (int h = 0; h < NH; ++h) {
        float temp = softplusf(tofnp[h] + rtwv[h] * len);
        float rl = act ? __fdividef(asp[h] - srnp[h] - dofnp[h] * len, temp + 1e-4f) : -1e30f;
        float tl = act ? (csp[h] - stnp[h]) : -1e30f;
        rm[h] = fmaxf(rm[h], rl); tm[h] = fmaxf(tm[h], tl);
      }
    }
    #pragma unroll
    for (int off = 32; off; off >>= 1)
      #pragma unroll
      for (int h = 0; h < NH; ++h) {
        rm[h] = fmaxf(rm[h], __shfl_xor(rm[h], off));
        tm[h] = fmaxf(tm[h], __shfl_xor(tm[h], off));
      }
    for (int base = i0; base < i1; base += 64) {
      int i = base + g; bool act = (i < i1);
      int s = act ? csnd[i] : 0; float len = act ? celen[i] : 0.f;
      float4 as4 = sr4[s], cs4 = st4[s];
      const float* asp = (const float*)&as4; const float* csp = (const float*)&cs4;
      #pragma unroll
      for (int h = 0; h < NH; ++h) {
        float temp = softplusf(tofnp[h] + rtwv[h] * len);
        float rl = act ? __fdividef(asp[h] - srnp[h] - dofnp[h] * len, temp + 1e-4f) : -1e30f;
        float tl = act ? (csp[h] - stnp[h]) : -1e30f;
        rs_[h] += act ? fexp(rl - rm[h]) : 0.f;
        ts_[h] += act ? fexp(tl - tm[h]) : 0.f;
      }
    }
    #pragma unroll
    for (int off = 32; off; off >>= 1)
      #pragma unroll
      for (int h = 0; h < NH; ++h) { rs_[h] += __shfl_xor(rs_[h], off); ts_[h] += __shfl_xor(ts_[h], off); }
    #pragma unroll
    for (int h = 0; h < NH; ++h) { rs_[h] = __fdividef(1.f, rs_[h] + 1e-9f); ts_[h] = __fdividef(1.f, ts_[h] + 1e-9f); }
    for (int base = i0; base < i1; base += 64) {
      int i = base + g; bool act = (i < i1);
      int s = act ? csnd[i] : 0; float len = act ? celen[i] : 0.f;
      float4 as4 = sr4[s], cs4 = st4[s];
      const float* asp = (const float*)&as4; const float* csp = (const float*)&cs4;
      #pragma unroll
      for (int h = 0; h < NH; ++h) {
        float temp = softplusf(tofnp[h] + rtwv[h] * len);
        float rl = act ? __fdividef(asp[h] - srnp[h] - dofnp[h] * len, temp + 1e-4f) : -1e30f;
        float tl = act ? (csp[h] - stnp[h]) : -1e30f;
        float gg = sigmoidf_(mbv[h] + msv[h] * len);
        float ar = (act ? fexp(rl - rm[h]) : 0.f) * rs_[h];
        float at = (act ? fexp(tl - tm[h]) : 0.f) * ts_[h];
        float ba = gg * ar + (1.f - gg) * at;
        float c1 = ba * gg, c2 = ba * (1.f - gg);
        coef_s[w][h][g] = c1; coef_s[w][4 + h][g] = c2;
        sc1[h] += c1; sc2[h] += c2;
      }
      snd_s[w][g] = s;
      int cnt = min(64, i1 - base);
      int j = 0;
      for (; j + 4 <= cnt; j += 4) {
        uint4 u0 = *(const uint4*)(ptb + ((size_t)snd_s[w][j]     * NF + g) * 8);
        uint4 u1 = *(const uint4*)(ptb + ((size_t)snd_s[w][j + 1] * NF + g) * 8);
        uint4 u2 = *(const uint4*)(ptb + ((size_t)snd_s[w][j + 2] * NF + g) * 8);
        uint4 u3 = *(const uint4*)(ptb + ((size_t)snd_s[w][j + 3] * NF + g) * 8);
        acc0 += dot8t(&coef_s[w][0][j],     u0);
        acc1 += dot8t(&coef_s[w][0][j + 1], u1);
        acc2 += dot8t(&coef_s[w][0][j + 2], u2);
        acc3 += dot8t(&coef_s[w][0][j + 3], u3);
      }
      for (; j < cnt; ++j) {
        uint4 u0 = *(const uint4*)(ptb + ((size_t)snd_s[w][j] * NF + g) * 8);
        acc0 += dot8t(&coef_s[w][0][j], u0);
      }
    }
  }

  float acc = (acc0 + acc1) + (acc2 + acc3);
  // reduce coefficient sums across the wave (each lane held its own edges' share)
  #pragma unroll
  for (int off = 32; off; off >>= 1)
    #pragma unroll
    for (int h = 0; h < NH; ++h) { sc1[h] += __shfl_xor(sc1[h], off); sc2[h] += __shfl_xor(sc2[h], off); }

  {
    uint4 uv = *(const uint4*)(ptb + ((size_t)n * NF + g) * 8);
    acc -= sc1[0] * bflo(uv.x) + sc1[1] * bfhi(uv.x)
         + sc1[2] * bflo(uv.y) + sc1[3] * bfhi(uv.y)
         + sc2[0] * bflo(uv.z) + sc2[1] * bfhi(uv.z)
         + sc2[2] * bflo(uv.w) + sc2[3] * bfhi(uv.w);
  }
  acc *= (1.f / NH);

  am_s[w][g] = acc;   // wave-local LDS; no block barrier needed
  float o = x[(size_t)n * NF + g];
  #pragma unroll 8
  for (int f = 0; f < NF; ++f) o += am_s[w][f] * wout_s[f * NF + g];
  out[(size_t)n * NF + g] = o;
}

extern "C" void kernel_launch(void* const* d_in, const int* in_sizes, int n_in,
                              void* d_out, int out_size, void* d_ws, size_t ws_size,
                              hipStream_t stream) {
  const float* x    = (const float*)d_in[0];
  const int*   ei   = (const int*)d_in[1];
  // d_in[2] = edge_vec, unused by the reference
  const float* elen = (const float*)d_in[3];
  const float* Wp   = (const float*)d_in[4];
  const float* Wr   = (const float*)d_in[5];
  const float* Wt   = (const float*)d_in[6];
  const float* rsc  = (const float*)d_in[7];
  const float* tsc  = (const float*)d_in[8];
  const float* rdls = (const float*)d_in[9];
  const float* rtb  = (const float*)d_in[10];
  const float* rtw  = (const float*)d_in[11];
  const float* mixb = (const float*)d_in[12];
  const float* mixs = (const float*)d_in[13];
  const float* dW1  = (const float*)d_in[14];
  const float* db1  = (const float*)d_in[15];
  const float* dw2  = (const float*)d_in[16];
  const float* db2  = (const float*)d_in[17];
  const float* tW1  = (const float*)d_in[18];
  const float* tb1  = (const float*)d_in[19];
  const float* tw2  = (const float*)d_in[20];
  const float* tb2  = (const float*)d_in[21];
  const float* Wout = (const float*)d_in[22];

  int N = in_sizes[0] / NF;
  int E = in_sizes[3];

  float* p = (float*)d_ws;
  unsigned short* Wpk = (unsigned short*)p; p += 32768;  // 128 frag x 64 lanes x 8 bf16 = 131072 B
  unsigned short* ptb = (unsigned short*)p; p += (size_t)N * NF * 8 / 2;  // [n][g][8] bf16
  float* sr   = p; p += (size_t)N * NH;
  float* st   = p; p += (size_t)N * NH;
  float* doff = p; p += (size_t)N * NH;
  float* toff = p; p += (size_t)N * NH;
  int* csnd   = (int*)p; p += E;              // CSR-ordered sender ids
  float* celen = p; p += E;                   // CSR-ordered edge lengths
  int* deg    = (int*)p; p += N;
  int* cursor = (int*)p; p += N;
  int* startp = (int*)p; p += N + 1;

  // K0: pack weights + zero deg/cursor (deg,cursor contiguous)
  k_pack<<<32, 256, 0, stream>>>(Wp, Wr, Wt, dW1, tW1, Wpk, deg, 2 * N);
  // K0b: degree count
  k_count<<<(E + 255) / 256, 256, 0, stream>>>(ei, deg, E);
  // K1: MFMA node pass
  k_projm<<<(N + NT - 1) / NT, 256, 0, stream>>>(x, Wpk, rsc, tsc, db1, dw2, db2,
                                                 tb1, tw2, tb2, rdls, rtb,
                                                 ptb, sr, st, doff, toff, N);
  // K2: scan degrees -> CSR starts
  k_scan<<<1, 1024, 0, stream>>>(deg, startp, N);
  // K3: CSR fill (snd + elen)
  k_fill<<<(E + 255) / 256, 256, 0, stream>>>(ei, elen, startp, cursor, csnd, celen, E);
  // K4: fused logits + softmax + aggregate + output
  k_aggout<<<(N + AW - 1) / AW, 512, 0, stream>>>(startp, csnd, celen,
                                                  (const float4*)sr, (const float4*)st,
                                                  (const float4*)doff, (const float4*)toff,
                                                  rtw, mixb, mixs, ptb, x, Wout, (float*)d_out, N);
}

// Round 21
// 140.573 us; speedup vs baseline: 1.1528x; 1.1528x over previous
//
#include <hip/hip_runtime.h>
#include <math.h>

#define NH 4
#define NF 64
#define NM 32
#define NT 16  // nodes per block in k_projm
#define SC 32  // elements per thread in k_scan (supports N <= 32768)
#define AW 8   // waves per block in k_aggout

typedef __attribute__((ext_vector_type(8))) short bf16x8;
typedef __attribute__((ext_vector_type(4))) float f32x4;

// fast transcendentals (hardware v_exp/v_log/v_rcp); absmax margin 0.03 vs 0.105 absorbs ~1e-6
__device__ __forceinline__ float fexp(float v){ return __expf(v); }
__device__ __forceinline__ float softplusf(float v){ return fmaxf(v, 0.f) + __logf(1.f + __expf(-fabsf(v))); }
__device__ __forceinline__ float sigmoidf_(float v){ return __fdividef(1.f, 1.f + __expf(-v)); }
__device__ __forceinline__ unsigned short f2bf(float f) {
  unsigned u = __float_as_uint(f);
  u = u + 0x7FFFu + ((u >> 16) & 1u);   // round-to-nearest-even
  return (unsigned short)(u >> 16);
}
__device__ __forceinline__ float bflo(unsigned u){ return __uint_as_float(u << 16); }
__device__ __forceinline__ float bfhi(unsigned u){ return __uint_as_float(u & 0xFFFF0000u); }

// ---------------- K0: pack weights into MFMA fragments + zero deg/cursor ----------------
__global__ void k_pack(const float* __restrict__ Wp, const float* __restrict__ Wr,
                       const float* __restrict__ Wt,
                       const float* __restrict__ dW1, const float* __restrict__ tW1,
                       unsigned short* __restrict__ Wpk, int* __restrict__ z, int nz) {
  int t = blockIdx.x * blockDim.x + threadIdx.x;   // 8192 threads
  for (int i = t; i < nz; i += 8192) z[i] = 0;
  int lane = t & 63;
  int frag = t >> 6;   // 0..127
  if (frag >= 128) return;
  if (frag < 96) {
    int nb = frag & 3, kb = (frag >> 2) & 1, h = (frag >> 3) & 3, q = frag >> 5;
    const float* W = (q == 0 ? Wp : (q == 1 ? Wr : Wt));
    int col = nb * 16 + (lane & 15);
    int krow = kb * 32 + (lane >> 4) * 8;
    #pragma unroll
    for (int j = 0; j < 8; ++j)
      Wpk[((size_t)frag * 64 + lane) * 8 + j] = f2bf(W[(size_t)h * NF * NF + (krow + j) * NF + col]);
  } else {
    int f2 = frag - 96;
    int nb = f2 & 1, kb = (f2 >> 1) & 1, h = (f2 >> 2) & 3, p2 = f2 >> 4;
    const float* W = (p2 == 0 ? dW1 : tW1);
    int col = nb * 16 + (lane & 15);
    int krow = kb * 32 + (lane >> 4) * 8;
    #pragma unroll
    for (int j = 0; j < 8; ++j)
      Wpk[((size_t)frag * 64 + lane) * 8 + j] = f2bf(W[(size_t)h * NF * NM + (krow + j) * NM + col]);
  }
}

// ---------------- K0b: degree count ----------------
__global__ void k_count(const int* __restrict__ ei, int* __restrict__ deg, int E) {
  int e = blockIdx.x * blockDim.x + threadIdx.x;
  if (e < E) atomicAdd(&deg[ei[E + e]], 1);
}

// ---------------- K1: MFMA node pass (pt stored bf16) ----------------
__global__ __launch_bounds__(256)
void k_projm(const float* __restrict__ x, const unsigned short* __restrict__ Wpk,
             const float* __restrict__ rsc, const float* __restrict__ tsc,
             const float* __restrict__ db1, const float* __restrict__ dw2, const float* __restrict__ db2,
             const float* __restrict__ tb1, const float* __restrict__ tw2, const float* __restrict__ tb2,
             const float* __restrict__ rdls, const float* __restrict__ rtb,
             unsigned short* __restrict__ ptb, float* __restrict__ sr, float* __restrict__ st,
             float* __restrict__ doff, float* __restrict__ toff, int N) {
  int n0 = blockIdx.x * NT;
  int tid = threadIdx.x;
  int h = tid >> 6, l = tid & 63;
  int lo = l & 15, hi = l >> 4;
  __shared__ __align__(16) unsigned short eps16[NH][16][72];  // bf16 ep, padded rows (144B)

  const bf16x8* W8 = (const bf16x8*)Wpk;

  bf16x8 a[2];
  {
    int nr = n0 + lo; if (nr >= N) nr = N - 1;
    const float* xr = x + (size_t)nr * NF + hi * 8;
    #pragma unroll
    for (int kb = 0; kb < 2; ++kb) {
      float4 v0 = *(const float4*)(xr + kb * 32);
      float4 v1 = *(const float4*)(xr + kb * 32 + 4);
      bf16x8 aa;
      aa[0] = (short)f2bf(v0.x); aa[1] = (short)f2bf(v0.y);
      aa[2] = (short)f2bf(v0.z); aa[3] = (short)f2bf(v0.w);
      aa[4] = (short)f2bf(v1.x); aa[5] = (short)f2bf(v1.y);
      aa[6] = (short)f2bf(v1.z); aa[7] = (short)f2bf(v1.w);
      a[kb] = aa;
    }
  }

  float srp[4] = {0.f,0.f,0.f,0.f}, stp[4] = {0.f,0.f,0.f,0.f};
  #pragma unroll
  for (int q = 0; q < 3; ++q) {
    #pragma unroll
    for (int nb = 0; nb < 4; ++nb) {
      f32x4 c = {0.f, 0.f, 0.f, 0.f};
      #pragma unroll
      for (int kb = 0; kb < 2; ++kb) {
        int frag = ((q * 4 + h) * 2 + kb) * 4 + nb;
        c = __builtin_amdgcn_mfma_f32_16x16x32_bf16(a[kb], W8[frag * 64 + l], c, 0, 0, 0);
      }
      int g = nb * 16 + lo;
      if (q == 0) {
        float rs = rsc[h * NF + g], ts = tsc[h * NF + g];
        #pragma unroll
        for (int r = 0; r < 4; ++r) {
          eps16[h][hi * 4 + r][g] = f2bf(c[r]);
          srp[r] += c[r] * rs;
          stp[r] += c[r] * ts;
        }
      } else {
        int row = (q - 1) * NH + h;
        #pragma unroll
        for (int r = 0; r < 4; ++r) {
          int n = n0 + hi * 4 + r;
          if (n < N) ptb[((size_t)n * NF + g) * 8 + row] = f2bf(c[r]);
        }
      }
    }
  }
  #pragma unroll
  for (int off = 1; off < 16; off <<= 1)
    #pragma unroll
    for (int r = 0; r < 4; ++r) { srp[r] += __shfl_xor(srp[r], off); stp[r] += __shfl_xor(stp[r], off); }
  if (lo == 0) {
    #pragma unroll
    for (int r = 0; r < 4; ++r) {
      int n = n0 + hi * 4 + r;
      if (n < N) { sr[n * NH + h] = srp[r]; st[n * NH + h] = stp[r]; }
    }
  }

  asm volatile("s_waitcnt lgkmcnt(0)" ::: "memory");
  bf16x8 ea[2];
  #pragma unroll
  for (int kb = 0; kb < 2; ++kb)
    ea[kb] = *(const bf16x8*)&eps16[h][lo][kb * 32 + hi * 8];

  float dpp[4] = {0.f,0.f,0.f,0.f}, tpp[4] = {0.f,0.f,0.f,0.f};
  #pragma unroll
  for (int p2 = 0; p2 < 2; ++p2) {
    #pragma unroll
    for (int nb = 0; nb < 2; ++nb) {
      f32x4 c = {0.f, 0.f, 0.f, 0.f};
      #pragma unroll
      for (int kb = 0; kb < 2; ++kb) {
        int frag = 96 + ((p2 * 4 + h) * 2 + kb) * 2 + nb;
        c = __builtin_amdgcn_mfma_f32_16x16x32_bf16(ea[kb], W8[frag * 64 + l], c, 0, 0, 0);
      }
      int m = nb * 16 + lo;
      float b1 = (p2 == 0 ? db1 : tb1)[h * NM + m];
      float w2 = (p2 == 0 ? dw2 : tw2)[h * NM + m];
      #pragma unroll
      for (int r = 0; r < 4; ++r) {
        float av = c[r] + b1;
        float sv = av * sigmoidf_(av) * w2;   // silu * w2
        if (p2 == 0) dpp[r] += sv; else tpp[r] += sv;
      }
    }
  }
  #pragma unroll
  for (int off = 1; off < 16; off <<= 1)
    #pragma unroll
    for (int r = 0; r < 4; ++r) { dpp[r] += __shfl_xor(dpp[r], off); tpp[r] += __shfl_xor(tpp[r], off); }
  if (lo == 0) {
    float dbase = db2[h] + softplusf(rdls[h]);
    float tbase = tb2[h] + rtb[h];
    #pragma unroll
    for (int r = 0; r < 4; ++r) {
      int n = n0 + hi * 4 + r;
      if (n < N) { doff[n * NH + h] = dpp[r] + dbase; toff[n * NH + h] = tpp[r] + tbase; }
    }
  }
}

// ---------------- K2: exclusive prefix scan (thread-serial + one tree) ----------------
__global__ void k_scan(const int* __restrict__ deg, int* __restrict__ start, int N) {
  __shared__ int sums[1024];
  int tid = threadIdx.x;
  int base = tid * SC;
  int local[SC];
  int s = 0;
  #pragma unroll
  for (int j = 0; j < SC; ++j) {
    int i = base + j;
    int v = (i < N) ? deg[i] : 0;
    local[j] = s;   // exclusive local prefix
    s += v;
  }
  sums[tid] = s;
  __syncthreads();
  for (int off = 1; off < 1024; off <<= 1) {
    int t = (tid >= off) ? sums[tid - off] : 0;
    __syncthreads();
    sums[tid] += t;
    __syncthreads();
  }
  int tbase = (tid > 0) ? sums[tid - 1] : 0;
  #pragma unroll
  for (int j = 0; j < SC; ++j) {
    int i = base + j;
    if (i < N) start[i] = tbase + local[j];
  }
  if (tid == 1023) start[N] = sums[1023];
}

// ---------------- K3: CSR fill (snd + elen only) ----------------
__global__ void k_fill(const int* __restrict__ ei, const float* __restrict__ elen,
                       const int* __restrict__ start, int* __restrict__ cursor,
                       int* __restrict__ csnd, float* __restrict__ celen, int E) {
  int e = blockIdx.x * blockDim.x + threadIdx.x;
  if (e >= E) return;
  int r = ei[E + e];
  int slot = start[r] + atomicAdd(&cursor[r], 1);
  csnd[slot] = ei[e];
  celen[slot] = elen[e];
}

// ---------------- K4: fused logits + softmax + gather-aggregate + Wout + residual ----------------
__device__ __forceinline__ float dot8(const float* cf, uint4 uv) {
  return cf[0] * bflo(uv.x) + cf[1] * bfhi(uv.x)
       + cf[2] * bflo(uv.y) + cf[3] * bfhi(uv.y)
       + cf[4] * bflo(uv.z) + cf[5] * bfhi(uv.z)
       + cf[6] * bflo(uv.w) + cf[7] * bfhi(uv.w);
}

__global__ __launch_bounds__(512)
void k_aggout(const int* __restrict__ start, const int* __restrict__ csnd, const float* __restrict__ celen,
              const float4* __restrict__ sr4, const float4* __restrict__ st4,
              const float4* __restrict__ doff4, const float4* __restrict__ toff4,
              const float* __restrict__ rtw, const float* __restrict__ mixb, const float* __restrict__ mixs,
              const unsigned short* __restrict__ ptb, const float* __restrict__ x,
              const float* __restrict__ Wout, float* __restrict__ out, int N) {
  __shared__ float wout_s[NF * NF];
  __shared__ float coef_s[AW][64][8];
  __shared__ int   snd_s[AW][64];
  __shared__ float am_s[AW][NF];
  int tid = threadIdx.x;
  {
    const float4* w4 = (const float4*)Wout;
    float4* s4 = (float4*)wout_s;
    for (int i = tid; i < NF * NF / 4; i += 512) s4[i] = w4[i];
  }
  __syncthreads();   // only block-wide barrier; everything after is wave-local
  int w = tid >> 6, g = tid & 63;
  int n = blockIdx.x * AW + w;
  if (n >= N) return;
  int i0 = start[n], i1 = start[n + 1];
  int deg = i1 - i0;

  // receiver-side broadcast values
  float4 srn = sr4[n], stn = st4[n], dofn = doff4[n], tofn = toff4[n];
  const float* srnp = (const float*)&srn; const float* stnp = (const float*)&stn;
  const float* dofnp = (const float*)&dofn; const float* tofnp = (const float*)&tofn;
  float rtwv[NH], mbv[NH], msv[NH];
  #pragma unroll
  for (int h = 0; h < NH; ++h) { rtwv[h] = rtw[h]; mbv[h] = mixb[h]; msv[h] = mixs[h]; }

  float rm[NH], tm[NH];
  float rs_[NH] = {0.f,0.f,0.f,0.f}, ts_[NH] = {0.f,0.f,0.f,0.f};
  float sc1[NH] = {0.f,0.f,0.f,0.f}, sc2[NH] = {0.f,0.f,0.f,0.f};
  float acc0 = 0.f, acc1 = 0.f, acc2 = 0.f, acc3 = 0.f;

  if (deg <= 64) {
    // ---------- fast path: lane = edge, logits live in registers ----------
    int i = i0 + g;
    bool act = (i < i1);
    int s = act ? csnd[i] : 0;
    float len = act ? celen[i] : 0.f;
    float4 as4 = sr4[s], cs4 = st4[s];
    const float* asp = (const float*)&as4; const float* csp = (const float*)&cs4;
    float rlv[NH], tlv[NH], gvv[NH];
    #pragma unroll
    for (int h = 0; h < NH; ++h) {
      float temp = softplusf(tofnp[h] + rtwv[h] * len);
      rlv[h] = act ? __fdividef(asp[h] - srnp[h] - dofnp[h] * len, temp + 1e-4f) : -1e30f;
      tlv[h] = act ? (csp[h] - stnp[h]) : -1e30f;
      gvv[h] = sigmoidf_(mbv[h] + msv[h] * len);
      rm[h] = rlv[h]; tm[h] = tlv[h];
    }
    #pragma unroll
    for (int off = 32; off; off >>= 1)
      #pragma unroll
      for (int h = 0; h < NH; ++h) {
        rm[h] = fmaxf(rm[h], __shfl_xor(rm[h], off));
        tm[h] = fmaxf(tm[h], __shfl_xor(tm[h], off));
      }
    float er[NH], et[NH];
    #pragma unroll
    for (int h = 0; h < NH; ++h) {
      er[h] = act ? fexp(rlv[h] - rm[h]) : 0.f;
      et[h] = act ? fexp(tlv[h] - tm[h]) : 0.f;
      rs_[h] = er[h]; ts_[h] = et[h];
    }
    #pragma unroll
    for (int off = 32; off; off >>= 1)
      #pragma unroll
      for (int h = 0; h < NH; ++h) { rs_[h] += __shfl_xor(rs_[h], off); ts_[h] += __shfl_xor(ts_[h], off); }
    #pragma unroll
    for (int h = 0; h < NH; ++h) { rs_[h] = __fdividef(1.f, rs_[h] + 1e-9f); ts_[h] = __fdividef(1.f, ts_[h] + 1e-9f); }
    #pragma unroll
    for (int h = 0; h < NH; ++h) {
      float ar = er[h] * rs_[h];
      float at = et[h] * ts_[h];
      float gg = gvv[h];
      float ba = gg * ar + (1.f - gg) * at;
      float c1 = ba * gg, c2 = ba * (1.f - gg);
      coef_s[w][g][h] = c1; coef_s[w][g][4 + h] = c2;
      sc1[h] = c1; sc2[h] = c2;   // inactive lanes: er=et=0 -> c1=c2=0
    }
    snd_s[w][g] = s;
    // gather (lane = feature, 4-way ILP)
    int j = 0;
    for (; j + 4 <= deg; j += 4) {
      uint4 u0 = *(const uint4*)(ptb + ((size_t)snd_s[w][j]     * NF + g) * 8);
      uint4 u1 = *(const uint4*)(ptb + ((size_t)snd_s[w][j + 1] * NF + g) * 8);
      uint4 u2 = *(const uint4*)(ptb + ((size_t)snd_s[w][j + 2] * NF + g) * 8);
      uint4 u3 = *(const uint4*)(ptb + ((size_t)snd_s[w][j + 3] * NF + g) * 8);
      acc0 += dot8(coef_s[w][j],     u0);
      acc1 += dot8(coef_s[w][j + 1], u1);
      acc2 += dot8(coef_s[w][j + 2], u2);
      acc3 += dot8(coef_s[w][j + 3], u3);
    }
    for (; j < deg; ++j) {
      uint4 u0 = *(const uint4*)(ptb + ((size_t)snd_s[w][j] * NF + g) * 8);
      acc0 += dot8(coef_s[w][j], u0);
    }
  } else {
    // ---------- slow path (deg > 64): chunked 3 passes, logits recomputed ----------
    #pragma unroll
    for (int h = 0; h < NH; ++h) { rm[h] = -1e30f; tm[h] = -1e30f; }
    for (int base = i0; base < i1; base += 64) {
      int i = base + g; bool act = (i < i1);
      int s = act ? csnd[i] : 0; float len = act ? celen[i] : 0.f;
      float4 as4 = sr4[s], cs4 = st4[s];
      const float* asp = (const float*)&as4; const float* csp = (const float*)&cs4;
      #pragma unroll
      for (int h = 0; h < NH; ++h) {
        float temp = softplusf(tofnp[h] + rtwv[h] * len);
        float rl = act ? __fdividef(asp[h] - srnp[h] - dofnp[h] * len, temp + 1e-4f) : -1e30f;
        float tl = act ? (csp[h] - stnp[h]) : -1e30f;
        rm[h] = fmaxf(rm[h], rl); tm[h] = fmaxf(tm[h], tl);
      }
    }
    #pragma unroll
    for (int off = 32; off; off >>= 1)
      #pragma unroll
      for (int h = 0; h < NH; ++h) {
        rm[h] = fmaxf(rm[h], __shfl_xor(rm[h], off));
        tm[h] = fmaxf(tm[h], __shfl_xor(tm[h], off));
      }
    for (int base = i0; base < i1; base += 64) {
      int i = base + g; bool act = (i < i1);
      int s = act ? csnd[i] : 0; float len = act ? celen[i] : 0.f;
      float4 as4 = sr4[s], cs4 = st4[s];
      const float* asp = (const float*)&as4; const float* csp = (const float*)&cs4;
      #pragma unroll
      for (int h = 0; h < NH; ++h) {
        float temp = softplusf(tofnp[h] + rtwv[h] * len);
        float rl = act ? __fdividef(asp[h] - srnp[h] - dofnp[h] * len, temp + 1e-4f) : -1e30f;
        float tl = act ? (csp[h] - stnp[h]) : -1e30f;
        rs_[h] += act ? fexp(rl - rm[h]) : 0.f;
        ts_[h] += act ? fexp(tl - tm[h]) : 0.f;
      }
    }
    #pragma unroll
    for (int off = 32; off; off >>= 1)
      #pragma unroll
      for (int h = 0; h < NH; ++h) { rs_[h] += __shfl_xor(rs_[h], off); ts_[h] += __shfl_xor(ts_[h], off); }
    #pragma unroll
    for (int h = 0; h < NH; ++h) { rs_[h] = __fdividef(1.f, rs_[h] + 1e-9f); ts_[h] = __fdividef(1.f, ts_[h] + 1e-9f); }
    for (int base = i0; base < i1; base += 64) {
      int i = base + g; bool act = (i < i1);
      int s = act ? csnd[i] : 0; float len = act ? celen[i] : 0.f;
      float4 as4 = sr4[s], cs4 = st4[s];
      const float* asp = (const float*)&as4; const float* csp = (const float*)&cs4;
      #pragma unroll
      for (int h = 0; h < NH; ++h) {
        float temp = softplusf(tofnp[h] + rtwv[h] * len);
        float rl = act ? __fdividef(asp[h] - srnp[h] - dofnp[h] * len, temp + 1e-4f) : -1e30f;
        float tl = act ? (csp[h] - stnp[h]) : -1e30f;
        float gg = sigmoidf_(mbv[h] + msv[h] * len);
        float ar = (act ? fexp(rl - rm[h]) : 0.f) * rs_[h];
        float at = (act ? fexp(tl - tm[h]) : 0.f) * ts_[h];
        float ba = gg * ar + (1.f - gg) * at;
        float c1 = ba * gg, c2 = ba * (1.f - gg);
        coef_s[w][g][h] = c1; coef_s[w][g][4 + h] = c2;
        sc1[h] += c1; sc2[h] += c2;
      }
      snd_s[w][g] = s;
      int cnt = min(64, i1 - base);
      int j = 0;
      for (; j + 4 <= cnt; j += 4) {
        uint4 u0 = *(const uint4*)(ptb + ((size_t)snd_s[w][j]     * NF + g) * 8);
        uint4 u1 = *(const uint4*)(ptb + ((size_t)snd_s[w][j + 1] * NF + g) * 8);
        uint4 u2 = *(const uint4*)(ptb + ((size_t)snd_s[w][j + 2] * NF + g) * 8);
        uint4 u3 = *(const uint4*)(ptb + ((size_t)snd_s[w][j + 3] * NF + g) * 8);
        acc0 += dot8(coef_s[w][j],     u0);
        acc1 += dot8(coef_s[w][j + 1], u1);
        acc2 += dot8(coef_s[w][j + 2], u2);
        acc3 += dot8(coef_s[w][j + 3], u3);
      }
      for (; j < cnt; ++j) {
        uint4 u0 = *(const uint4*)(ptb + ((size_t)snd_s[w][j] * NF + g) * 8);
        acc0 += dot8(coef_s[w][j], u0);
      }
    }
  }

  float acc = (acc0 + acc1) + (acc2 + acc3);
  // reduce coefficient sums across the wave (each lane held its own edges' share)
  #pragma unroll
  for (int off = 32; off; off >>= 1)
    #pragma unroll
    for (int h = 0; h < NH; ++h) { sc1[h] += __shfl_xor(sc1[h], off); sc2[h] += __shfl_xor(sc2[h], off); }

  {
    uint4 uv = *(const uint4*)(ptb + ((size_t)n * NF + g) * 8);
    acc -= sc1[0] * bflo(uv.x) + sc1[1] * bfhi(uv.x)
         + sc1[2] * bflo(uv.y) + sc1[3] * bfhi(uv.y)
         + sc2[0] * bflo(uv.z) + sc2[1] * bfhi(uv.z)
         + sc2[2] * bflo(uv.w) + sc2[3] * bfhi(uv.w);
  }
  acc *= (1.f / NH);

  am_s[w][g] = acc;   // wave-local LDS; no block barrier needed
  float o = x[(size_t)n * NF + g];
  #pragma unroll 8
  for (int f = 0; f < NF; ++f) o += am_s[w][f] * wout_s[f * NF + g];
  out[(size_t)n * NF + g] = o;
}

extern "C" void kernel_launch(void* const* d_in, const int* in_sizes, int n_in,
                              void* d_out, int out_size, void* d_ws, size_t ws_size,
                              hipStream_t stream) {
  const float* x    = (const float*)d_in[0];
  const int*   ei   = (const int*)d_in[1];
  // d_in[2] = edge_vec, unused by the reference
  const float* elen = (const float*)d_in[3];
  const float* Wp   = (const float*)d_in[4];
  const float* Wr   = (const float*)d_in[5];
  const float* Wt   = (const float*)d_in[6];
  const float* rsc  = (const float*)d_in[7];
  const float* tsc  = (const float*)d_in[8];
  const float* rdls = (const float*)d_in[9];
  const float* rtb  = (const float*)d_in[10];
  const float* rtw  = (const float*)d_in[11];
  const float* mixb = (const float*)d_in[12];
  const float* mixs = (const float*)d_in[13];
  const float* dW1  = (const float*)d_in[14];
  const float* db1  = (const float*)d_in[15];
  const float* dw2  = (const float*)d_in[16];
  const float* db2  = (const float*)d_in[17];
  const float* tW1  = (const float*)d_in[18];
  const float* tb1  = (const float*)d_in[19];
  const float* tw2  = (const float*)d_in[20];
  const float* tb2  = (const float*)d_in[21];
  const float* Wout = (const float*)d_in[22];

  int N = in_sizes[0] / NF;
  int E = in_sizes[3];

  float* p = (float*)d_ws;
  unsigned short* Wpk = (unsigned short*)p; p += 32768;  // 128 frag x 64 lanes x 8 bf16 = 131072 B
  unsigned short* ptb = (unsigned short*)p; p += (size_t)N * NF * 8 / 2;  // [n][g][8] bf16
  float* sr   = p; p += (size_t)N * NH;
  float* st   = p; p += (size_t)N * NH;
  float* doff = p; p += (size_t)N * NH;
  float* toff = p; p += (size_t)N * NH;
  int* csnd   = (int*)p; p += E;              // CSR-ordered sender ids
  float* celen = p; p += E;                   // CSR-ordered edge lengths
  int* deg    = (int*)p; p += N;
  int* cursor = (int*)p; p += N;
  int* startp = (int*)p; p += N + 1;

  // K0: pack weights + zero deg/cursor (deg,cursor contiguous)
  k_pack<<<32, 256, 0, stream>>>(Wp, Wr, Wt, dW1, tW1, Wpk, deg, 2 * N);
  // K0b: degree count
  k_count<<<(E + 255) / 256, 256, 0, stream>>>(ei, deg, E);
  // K1: MFMA node pass
  k_projm<<<(N + NT - 1) / NT, 256, 0, stream>>>(x, Wpk, rsc, tsc, db1, dw2, db2,
                                                 tb1, tw2, tb2, rdls, rtb,
                                                 ptb, sr, st, doff, toff, N);
  // K2: scan degrees -> CSR starts
  k_scan<<<1, 1024, 0, stream>>>(deg, startp, N);
  // K3: CSR fill (snd + elen)
  k_fill<<<(E + 255) / 256, 256, 0, stream>>>(ei, elen, startp, cursor, csnd, celen, E);
  // K4: fused logits + softmax + aggregate + output
  k_aggout<<<(N + AW - 1) / AW, 512, 0, stream>>>(startp, csnd, celen,
                                                  (const float4*)sr, (const float4*)st,
                                                  (const float4*)doff, (const float4*)toff,
                                                  rtw, mixb, mixs, ptb, x, Wout, (float*)d_out, N);
}

// Round 22
// 124.693 us; speedup vs baseline: 1.2996x; 1.1274x over previous
//
#include <hip/hip_runtime.h>
#include <math.h>

#define NH 4
#define NF 64
#define NM 32
#define NT 16  // nodes per block in k_projm
#define SC 32  // elements per thread in k_scan (supports N <= 32768)
#define AW 8   // waves per block in k_aggout

typedef __attribute__((ext_vector_type(8))) short bf16x8;
typedef __attribute__((ext_vector_type(4))) float f32x4;

// fast transcendentals (hardware v_exp/v_log/v_rcp); absmax margin 0.03 vs 0.105 absorbs ~1e-6
__device__ __forceinline__ float fexp(float v){ return __expf(v); }
__device__ __forceinline__ float softplusf(float v){ return fmaxf(v, 0.f) + __logf(1.f + __expf(-fabsf(v))); }
__device__ __forceinline__ float sigmoidf_(float v){ return __fdividef(1.f, 1.f + __expf(-v)); }
__device__ __forceinline__ unsigned short f2bf(float f) {
  unsigned u = __float_as_uint(f);
  u = u + 0x7FFFu + ((u >> 16) & 1u);   // round-to-nearest-even
  return (unsigned short)(u >> 16);
}
__device__ __forceinline__ float bflo(unsigned u){ return __uint_as_float(u << 16); }
__device__ __forceinline__ float bfhi(unsigned u){ return __uint_as_float(u & 0xFFFF0000u); }

// ---------------- K0: pack weights into MFMA fragments + zero deg ----------------
__global__ void k_pack(const float* __restrict__ Wp, const float* __restrict__ Wr,
                       const float* __restrict__ Wt,
                       const float* __restrict__ dW1, const float* __restrict__ tW1,
                       unsigned short* __restrict__ Wpk, int* __restrict__ z, int nz) {
  int t = blockIdx.x * blockDim.x + threadIdx.x;   // 8192 threads
  for (int i = t; i < nz; i += 8192) z[i] = 0;
  int lane = t & 63;
  int frag = t >> 6;   // 0..127
  if (frag >= 128) return;
  if (frag < 96) {
    int nb = frag & 3, kb = (frag >> 2) & 1, h = (frag >> 3) & 3, q = frag >> 5;
    const float* W = (q == 0 ? Wp : (q == 1 ? Wr : Wt));
    int col = nb * 16 + (lane & 15);
    int krow = kb * 32 + (lane >> 4) * 8;
    #pragma unroll
    for (int j = 0; j < 8; ++j)
      Wpk[((size_t)frag * 64 + lane) * 8 + j] = f2bf(W[(size_t)h * NF * NF + (krow + j) * NF + col]);
  } else {
    int f2 = frag - 96;
    int nb = f2 & 1, kb = (f2 >> 1) & 1, h = (f2 >> 2) & 3, p2 = f2 >> 4;
    const float* W = (p2 == 0 ? dW1 : tW1);
    int col = nb * 16 + (lane & 15);
    int krow = kb * 32 + (lane >> 4) * 8;
    #pragma unroll
    for (int j = 0; j < 8; ++j)
      Wpk[((size_t)frag * 64 + lane) * 8 + j] = f2bf(W[(size_t)h * NF * NM + (krow + j) * NM + col]);
  }
}

// ---------------- K0b: degree count (saves slot-within-receiver) ----------------
__global__ void k_count(const int* __restrict__ ei, int* __restrict__ deg,
                        int* __restrict__ slotw, int E) {
  int e = blockIdx.x * blockDim.x + threadIdx.x;
  if (e < E) slotw[e] = atomicAdd(&deg[ei[E + e]], 1);
}

// ---------------- K1: MFMA node pass (pt stored bf16, LDS-staged coalesced writes) ----------------
__global__ __launch_bounds__(256)
void k_projm(const float* __restrict__ x, const unsigned short* __restrict__ Wpk,
             const float* __restrict__ rsc, const float* __restrict__ tsc,
             const float* __restrict__ db1, const float* __restrict__ dw2, const float* __restrict__ db2,
             const float* __restrict__ tb1, const float* __restrict__ tw2, const float* __restrict__ tb2,
             const float* __restrict__ rdls, const float* __restrict__ rtb,
             unsigned short* __restrict__ ptb, float* __restrict__ sr, float* __restrict__ st,
             float* __restrict__ doff, float* __restrict__ toff, int N) {
  int n0 = blockIdx.x * NT;
  int tid = threadIdx.x;
  int h = tid >> 6, l = tid & 63;
  int lo = l & 15, hi = l >> 4;
  __shared__ __align__(16) unsigned short eps16[NH][16][72];  // bf16 ep, padded rows
  __shared__ __align__(16) unsigned short pts[NT][NF][8];     // staged rp/tp (16 KB)

  const bf16x8* W8 = (const bf16x8*)Wpk;

  bf16x8 a[2];
  {
    int nr = n0 + lo; if (nr >= N) nr = N - 1;
    const float* xr = x + (size_t)nr * NF + hi * 8;
    #pragma unroll
    for (int kb = 0; kb < 2; ++kb) {
      float4 v0 = *(const float4*)(xr + kb * 32);
      float4 v1 = *(const float4*)(xr + kb * 32 + 4);
      bf16x8 aa;
      aa[0] = (short)f2bf(v0.x); aa[1] = (short)f2bf(v0.y);
      aa[2] = (short)f2bf(v0.z); aa[3] = (short)f2bf(v0.w);
      aa[4] = (short)f2bf(v1.x); aa[5] = (short)f2bf(v1.y);
      aa[6] = (short)f2bf(v1.z); aa[7] = (short)f2bf(v1.w);
      a[kb] = aa;
    }
  }

  float srp[4] = {0.f,0.f,0.f,0.f}, stp[4] = {0.f,0.f,0.f,0.f};
  #pragma unroll
  for (int q = 0; q < 3; ++q) {
    #pragma unroll
    for (int nb = 0; nb < 4; ++nb) {
      f32x4 c = {0.f, 0.f, 0.f, 0.f};
      #pragma unroll
      for (int kb = 0; kb < 2; ++kb) {
        int frag = ((q * 4 + h) * 2 + kb) * 4 + nb;
        c = __builtin_amdgcn_mfma_f32_16x16x32_bf16(a[kb], W8[frag * 64 + l], c, 0, 0, 0);
      }
      int g = nb * 16 + lo;
      if (q == 0) {
        float rs = rsc[h * NF + g], ts = tsc[h * NF + g];
        #pragma unroll
        for (int r = 0; r < 4; ++r) {
          eps16[h][hi * 4 + r][g] = f2bf(c[r]);
          srp[r] += c[r] * rs;
          stp[r] += c[r] * ts;
        }
      } else {
        int row = (q - 1) * NH + h;
        #pragma unroll
        for (int r = 0; r < 4; ++r)
          pts[hi * 4 + r][g][row] = f2bf(c[r]);   // 2-way LDS bank alias: free
      }
    }
  }
  #pragma unroll
  for (int off = 1; off < 16; off <<= 1)
    #pragma unroll
    for (int r = 0; r < 4; ++r) { srp[r] += __shfl_xor(srp[r], off); stp[r] += __shfl_xor(stp[r], off); }
  if (lo == 0) {
    #pragma unroll
    for (int r = 0; r < 4; ++r) {
      int n = n0 + hi * 4 + r;
      if (n < N) { sr[n * NH + h] = srp[r]; st[n * NH + h] = stp[r]; }
    }
  }

  asm volatile("s_waitcnt lgkmcnt(0)" ::: "memory");
  bf16x8 ea[2];
  #pragma unroll
  for (int kb = 0; kb < 2; ++kb)
    ea[kb] = *(const bf16x8*)&eps16[h][lo][kb * 32 + hi * 8];

  float dpp[4] = {0.f,0.f,0.f,0.f}, tpp[4] = {0.f,0.f,0.f,0.f};
  #pragma unroll
  for (int p2 = 0; p2 < 2; ++p2) {
    #pragma unroll
    for (int nb = 0; nb < 2; ++nb) {
      f32x4 c = {0.f, 0.f, 0.f, 0.f};
      #pragma unroll
      for (int kb = 0; kb < 2; ++kb) {
        int frag = 96 + ((p2 * 4 + h) * 2 + kb) * 2 + nb;
        c = __builtin_amdgcn_mfma_f32_16x16x32_bf16(ea[kb], W8[frag * 64 + l], c, 0, 0, 0);
      }
      int m = nb * 16 + lo;
      float b1 = (p2 == 0 ? db1 : tb1)[h * NM + m];
      float w2 = (p2 == 0 ? dw2 : tw2)[h * NM + m];
      #pragma unroll
      for (int r = 0; r < 4; ++r) {
        float av = c[r] + b1;
        float sv = av * sigmoidf_(av) * w2;   // silu * w2
        if (p2 == 0) dpp[r] += sv; else tpp[r] += sv;
      }
    }
  }
  #pragma unroll
  for (int off = 1; off < 16; off <<= 1)
    #pragma unroll
    for (int r = 0; r < 4; ++r) { dpp[r] += __shfl_xor(dpp[r], off); tpp[r] += __shfl_xor(tpp[r], off); }
  if (lo == 0) {
    float dbase = db2[h] + softplusf(rdls[h]);
    float tbase = tb2[h] + rtb[h];
    #pragma unroll
    for (int r = 0; r < 4; ++r) {
      int n = n0 + hi * 4 + r;
      if (n < N) { doff[n * NH + h] = dpp[r] + dbase; toff[n * NH + h] = tpp[r] + tbase; }
    }
  }

  // coalesced ptb flush: 1024 uint4 (one per (n,g)), contiguous 16B stores
  __syncthreads();
  for (int i = tid; i < NT * NF; i += 256) {
    int n = i >> 6, gg = i & 63;
    int gn = n0 + n;
    if (gn < N)
      *(uint4*)(ptb + ((size_t)gn * NF + gg) * 8) = *(const uint4*)&pts[n][gg][0];
  }
}

// ---------------- K2: exclusive prefix scan (thread-serial + one tree) ----------------
__global__ void k_scan(const int* __restrict__ deg, int* __restrict__ start, int N) {
  __shared__ int sums[1024];
  int tid = threadIdx.x;
  int base = tid * SC;
  int local[SC];
  int s = 0;
  #pragma unroll
  for (int j = 0; j < SC; ++j) {
    int i = base + j;
    int v = (i < N) ? deg[i] : 0;
    local[j] = s;   // exclusive local prefix
    s += v;
  }
  sums[tid] = s;
  __syncthreads();
  for (int off = 1; off < 1024; off <<= 1) {
    int t = (tid >= off) ? sums[tid - off] : 0;
    __syncthreads();
    sums[tid] += t;
    __syncthreads();
  }
  int tbase = (tid > 0) ? sums[tid - 1] : 0;
  #pragma unroll
  for (int j = 0; j < SC; ++j) {
    int i = base + j;
    if (i < N) start[i] = tbase + local[j];
  }
  if (tid == 1023) start[N] = sums[1023];
}

// ---------------- K3: CSR fill (no atomics; int2 combined store) ----------------
__global__ void k_fill(const int* __restrict__ ei, const float* __restrict__ elen,
                       const int* __restrict__ start, const int* __restrict__ slotw,
                       int2* __restrict__ cse, int E) {
  int e = blockIdx.x * blockDim.x + threadIdx.x;
  if (e >= E) return;
  int r = ei[E + e];
  int slot = start[r] + slotw[e];
  cse[slot] = make_int2(ei[e], __float_as_int(elen[e]));
}

// ---------------- K4: fused logits + softmax + gather-aggregate + Wout + residual ----------------
__device__ __forceinline__ float dot8(const float* cf, uint4 uv) {
  return cf[0] * bflo(uv.x) + cf[1] * bfhi(uv.x)
       + cf[2] * bflo(uv.y) + cf[3] * bfhi(uv.y)
       + cf[4] * bflo(uv.z) + cf[5] * bfhi(uv.z)
       + cf[6] * bflo(uv.w) + cf[7] * bfhi(uv.w);
}

__global__ __launch_bounds__(512)
void k_aggout(const int* __restrict__ start, const int2* __restrict__ cse,
              const float4* __restrict__ sr4, const float4* __restrict__ st4,
              const float4* __restrict__ doff4, const float4* __restrict__ toff4,
              const float* __restrict__ rtw, const float* __restrict__ mixb, const float* __restrict__ mixs,
              const unsigned short* __restrict__ ptb, const float* __restrict__ x,
              const float* __restrict__ Wout, float* __restrict__ out, int N) {
  __shared__ float wout_s[NF * NF];
  __shared__ float coef_s[AW][64][8];
  __shared__ int   snd_s[AW][64];
  __shared__ float am_s[AW][NF];
  int tid = threadIdx.x;
  {
    const float4* w4 = (const float4*)Wout;
    float4* s4 = (float4*)wout_s;
    for (int i = tid; i < NF * NF / 4; i += 512) s4[i] = w4[i];
  }
  __syncthreads();   // only block-wide barrier; everything after is wave-local
  int w = tid >> 6, g = tid & 63;
  int n = blockIdx.x * AW + w;
  if (n >= N) return;
  int i0 = start[n], i1 = start[n + 1];
  int deg = i1 - i0;

  float4 srn = sr4[n], stn = st4[n], dofn = doff4[n], tofn = toff4[n];
  const float* srnp = (const float*)&srn; const float* stnp = (const float*)&stn;
  const float* dofnp = (const float*)&dofn; const float* tofnp = (const float*)&tofn;
  float rtwv[NH], mbv[NH], msv[NH];
  #pragma unroll
  for (int h = 0; h < NH; ++h) { rtwv[h] = rtw[h]; mbv[h] = mixb[h]; msv[h] = mixs[h]; }

  float rm[NH], tm[NH];
  float rs_[NH] = {0.f,0.f,0.f,0.f}, ts_[NH] = {0.f,0.f,0.f,0.f};
  float sc1[NH] = {0.f,0.f,0.f,0.f}, sc2[NH] = {0.f,0.f,0.f,0.f};
  float acc0 = 0.f, acc1 = 0.f, acc2 = 0.f, acc3 = 0.f;

  if (deg <= 64) {
    // ---------- fast path: lane = edge, logits live in registers ----------
    int i = i0 + g;
    bool act = (i < i1);
    int2 sv = act ? cse[i] : make_int2(0, 0);
    int s = sv.x;
    float len = __int_as_float(sv.y);
    float4 as4 = sr4[s], cs4 = st4[s];
    const float* asp = (const float*)&as4; const float* csp = (const float*)&cs4;
    float rlv[NH], tlv[NH], gvv[NH];
    #pragma unroll
    for (int h = 0; h < NH; ++h) {
      float temp = softplusf(tofnp[h] + rtwv[h] * len);
      rlv[h] = act ? __fdividef(asp[h] - srnp[h] - dofnp[h] * len, temp + 1e-4f) : -1e30f;
      tlv[h] = act ? (csp[h] - stnp[h]) : -1e30f;
      gvv[h] = sigmoidf_(mbv[h] + msv[h] * len);
      rm[h] = rlv[h]; tm[h] = tlv[h];
    }
    #pragma unroll
    for (int off = 32; off; off >>= 1)
      #pragma unroll
      for (int h = 0; h < NH; ++h) {
        rm[h] = fmaxf(rm[h], __shfl_xor(rm[h], off));
        tm[h] = fmaxf(tm[h], __shfl_xor(tm[h], off));
      }
    float er[NH], et[NH];
    #pragma unroll
    for (int h = 0; h < NH; ++h) {
      er[h] = act ? fexp(rlv[h] - rm[h]) : 0.f;
      et[h] = act ? fexp(tlv[h] - tm[h]) : 0.f;
      rs_[h] = er[h]; ts_[h] = et[h];
    }
    #pragma unroll
    for (int off = 32; off; off >>= 1)
      #pragma unroll
      for (int h = 0; h < NH; ++h) { rs_[h] += __shfl_xor(rs_[h], off); ts_[h] += __shfl_xor(ts_[h], off); }
    #pragma unroll
    for (int h = 0; h < NH; ++h) { rs_[h] = __fdividef(1.f, rs_[h] + 1e-9f); ts_[h] = __fdividef(1.f, ts_[h] + 1e-9f); }
    #pragma unroll
    for (int h = 0; h < NH; ++h) {
      float ar = er[h] * rs_[h];
      float at = et[h] * ts_[h];
      float gg = gvv[h];
      float ba = gg * ar + (1.f - gg) * at;
      float c1 = ba * gg, c2 = ba * (1.f - gg);
      coef_s[w][g][h] = c1; coef_s[w][g][4 + h] = c2;
      sc1[h] = c1; sc2[h] = c2;   // inactive lanes: er=et=0 -> c1=c2=0
    }
    snd_s[w][g] = s;
    int j = 0;
    for (; j + 4 <= deg; j += 4) {
      uint4 u0 = *(const uint4*)(ptb + ((size_t)snd_s[w][j]     * NF + g) * 8);
      uint4 u1 = *(const uint4*)(ptb + ((size_t)snd_s[w][j + 1] * NF + g) * 8);
      uint4 u2 = *(const uint4*)(ptb + ((size_t)snd_s[w][j + 2] * NF + g) * 8);
      uint4 u3 = *(const uint4*)(ptb + ((size_t)snd_s[w][j + 3] * NF + g) * 8);
      acc0 += dot8(coef_s[w][j],     u0);
      acc1 += dot8(coef_s[w][j + 1], u1);
      acc2 += dot8(coef_s[w][j + 2], u2);
      acc3 += dot8(coef_s[w][j + 3], u3);
    }
    for (; j < deg; ++j) {
      uint4 u0 = *(const uint4*)(ptb + ((size_t)snd_s[w][j] * NF + g) * 8);
      acc0 += dot8(coef_s[w][j], u0);
    }
  } else {
    // ---------- slow path (deg > 64): chunked 3 passes, logits recomputed ----------
    #pragma unroll
    for (int h = 0; h < NH; ++h) { rm[h] = -1e30f; tm[h] = -1e30f; }
    for (int base = i0; base < i1; base += 64) {
      int i = base + g; bool act = (i < i1);
      int2 sv = act ? cse[i] : make_int2(0, 0);
      int s = sv.x; float len = __int_as_float(sv.y);
      float4 as4 = sr4[s], cs4 = st4[s];
      const float* asp = (const float*)&as4; const float* csp = (const float*)&cs4;
      #pragma unroll
      for (int h = 0; h < NH; ++h) {
        float temp = softplusf(tofnp[h] + rtwv[h] * len);
        float rl = act ? __fdividef(asp[h] - srnp[h] - dofnp[h] * len, temp + 1e-4f) : -1e30f;
        float tl = act ? (csp[h] - stnp[h]) : -1e30f;
        rm[h] = fmaxf(rm[h], rl); tm[h] = fmaxf(tm[h], tl);
      }
    }
    #pragma unroll
    for (int off = 32; off; off >>= 1)
      #pragma unroll
      for (int h = 0; h < NH; ++h) {
        rm[h] = fmaxf(rm[h], __shfl_xor(rm[h], off));
        tm[h] = fmaxf(tm[h], __shfl_xor(tm[h], off));
      }
    for (int base = i0; base < i1; base += 64) {
      int i = base + g; bool act = (i < i1);
      int2 sv = act ? cse[i] : make_int2(0, 0);
      int s = sv.x; float len = __int_as_float(sv.y);
      float4 as4 = sr4[s], cs4 = st4[s];
      const float* asp = (const float*)&as4; const float* csp = (const float*)&cs4;
      #pragma unroll
      for (int h = 0; h < NH; ++h) {
        float temp = softplusf(tofnp[h] + rtwv[h] * len);
        float rl = act ? __fdividef(asp[h] - srnp[h] - dofnp[h] * len, temp + 1e-4f) : -1e30f;
        float tl = act ? (csp[h] - stnp[h]) : -1e30f;
        rs_[h] += act ? fexp(rl - rm[h]) : 0.f;
        ts_[h] += act ? fexp(tl - tm[h]) : 0.f;
      }
    }
    #pragma unroll
    for (int off = 32; off; off >>= 1)
      #pragma unroll
      for (int h = 0; h < NH; ++h) { rs_[h] += __shfl_xor(rs_[h], off); ts_[h] += __shfl_xor(ts_[h], off); }
    #pragma unroll
    for (int h = 0; h < NH; ++h) { rs_[h] = __fdividef(1.f, rs_[h] + 1e-9f); ts_[h] = __fdividef(1.f, ts_[h] + 1e-9f); }
    for (int base = i0; base < i1; base += 64) {
      int i = base + g; bool act = (i < i1);
      int2 sv = act ? cse[i] : make_int2(0, 0);
      int s = sv.x; float len = __int_as_float(sv.y);
      float4 as4 = sr4[s], cs4 = st4[s];
      const float* asp = (const float*)&as4; const float* csp = (const float*)&cs4;
      #pragma unroll
      for (int h = 0; h < NH; ++h) {
        float temp = softplusf(tofnp[h] + rtwv[h] * len);
        float rl = act ? __fdividef(asp[h] - srnp[h] - dofnp[h] * len, temp + 1e-4f) : -1e30f;
        float tl = act ? (csp[h] - stnp[h]) : -1e30f;
        float gg = sigmoidf_(mbv[h] + msv[h] * len);
        float ar = (act ? fexp(rl - rm[h]) : 0.f) * rs_[h];
        float at = (act ? fexp(tl - tm[h]) : 0.f) * ts_[h];
        float ba = gg * ar + (1.f - gg) * at;
        float c1 = ba * gg, c2 = ba * (1.f - gg);
        coef_s[w][g][h] = c1; coef_s[w][g][4 + h] = c2;
        sc1[h] += c1; sc2[h] += c2;
      }
      snd_s[w][g] = s;
      int cnt = min(64, i1 - base);
      int j = 0;
      for (; j + 4 <= cnt; j += 4) {
        uint4 u0 = *(const uint4*)(ptb + ((size_t)snd_s[w][j]     * NF + g) * 8);
        uint4 u1 = *(const uint4*)(ptb + ((size_t)snd_s[w][j + 1] * NF + g) * 8);
        uint4 u2 = *(const uint4*)(ptb + ((size_t)snd_s[w][j + 2] * NF + g) * 8);
        uint4 u3 = *(const uint4*)(ptb + ((size_t)snd_s[w][j + 3] * NF + g) * 8);
        acc0 += dot8(coef_s[w][j],     u0);
        acc1 += dot8(coef_s[w][j + 1], u1);
        acc2 += dot8(coef_s[w][j + 2], u2);
        acc3 += dot8(coef_s[w][j + 3], u3);
      }
      for (; j < cnt; ++j) {
        uint4 u0 = *(const uint4*)(ptb + ((size_t)snd_s[w][j] * NF + g) * 8);
        acc0 += dot8(coef_s[w][j], u0);
      }
    }
  }

  float acc = (acc0 + acc1) + (acc2 + acc3);
  #pragma unroll
  for (int off = 32; off; off >>= 1)
    #pragma unroll
    for (int h = 0; h < NH; ++h) { sc1[h] += __shfl_xor(sc1[h], off); sc2[h] += __shfl_xor(sc2[h], off); }

  {
    uint4 uv = *(const uint4*)(ptb + ((size_t)n * NF + g) * 8);
    acc -= sc1[0] * bflo(uv.x) + sc1[1] * bfhi(uv.x)
         + sc1[2] * bflo(uv.y) + sc1[3] * bfhi(uv.y)
         + sc2[0] * bflo(uv.z) + sc2[1] * bfhi(uv.z)
         + sc2[2] * bflo(uv.w) + sc2[3] * bfhi(uv.w);
  }
  acc *= (1.f / NH);

  am_s[w][g] = acc;   // wave-local LDS; no block barrier needed
  float o = x[(size_t)n * NF + g];
  #pragma unroll 8
  for (int f = 0; f < NF; ++f) o += am_s[w][f] * wout_s[f * NF + g];
  out[(size_t)n * NF + g] = o;
}

extern "C" void kernel_launch(void* const* d_in, const int* in_sizes, int n_in,
                              void* d_out, int out_size, void* d_ws, size_t ws_size,
                              hipStream_t stream) {
  const float* x    = (const float*)d_in[0];
  const int*   ei   = (const int*)d_in[1];
  // d_in[2] = edge_vec, unused by the reference
  const float* elen = (const float*)d_in[3];
  const float* Wp   = (const float*)d_in[4];
  const float* Wr   = (const float*)d_in[5];
  const float* Wt   = (const float*)d_in[6];
  const float* rsc  = (const float*)d_in[7];
  const float* tsc  = (const float*)d_in[8];
  const float* rdls = (const float*)d_in[9];
  const float* rtb  = (const float*)d_in[10];
  const float* rtw  = (const float*)d_in[11];
  const float* mixb = (const float*)d_in[12];
  const float* mixs = (const float*)d_in[13];
  const float* dW1  = (const float*)d_in[14];
  const float* db1  = (const float*)d_in[15];
  const float* dw2  = (const float*)d_in[16];
  const float* db2  = (const float*)d_in[17];
  const float* tW1  = (const float*)d_in[18];
  const float* tb1  = (const float*)d_in[19];
  const float* tw2  = (const float*)d_in[20];
  const float* tb2  = (const float*)d_in[21];
  const float* Wout = (const float*)d_in[22];

  int N = in_sizes[0] / NF;
  int E = in_sizes[3];

  float* p = (float*)d_ws;
  unsigned short* Wpk = (unsigned short*)p; p += 32768;  // 128 frag x 64 lanes x 8 bf16 = 131072 B
  unsigned short* ptb = (unsigned short*)p; p += (size_t)N * NF * 8 / 2;  // [n][g][8] bf16
  float* sr   = p; p += (size_t)N * NH;
  float* st   = p; p += (size_t)N * NH;
  float* doff = p; p += (size_t)N * NH;
  float* toff = p; p += (size_t)N * NH;
  int2* cse   = (int2*)p; p += (size_t)2 * E;  // CSR-ordered {sender, elen}
  int* slotw  = (int*)p; p += E;               // slot-within-receiver per edge
  int* deg    = (int*)p; p += N;
  int* startp = (int*)p; p += N + 1;

  // K0: pack weights + zero deg
  k_pack<<<32, 256, 0, stream>>>(Wp, Wr, Wt, dW1, tW1, Wpk, deg, N);
  // K0b: degree count (+slot within receiver)
  k_count<<<(E + 255) / 256, 256, 0, stream>>>(ei, deg, slotw, E);
  // K1: MFMA node pass
  k_projm<<<(N + NT - 1) / NT, 256, 0, stream>>>(x, Wpk, rsc, tsc, db1, dw2, db2,
                                                 tb1, tw2, tb2, rdls, rtb,
                                                 ptb, sr, st, doff, toff, N);
  // K2: scan degrees -> CSR starts
  k_scan<<<1, 1024, 0, stream>>>(deg, startp, N);
  // K3: CSR fill (no atomics)
  k_fill<<<(E + 255) / 256, 256, 0, stream>>>(ei, elen, startp, slotw, cse, E);
  // K4: fused logits + softmax + aggregate + output
  k_aggout<<<(N + AW - 1) / AW, 512, 0, stream>>>(startp, cse,
                                                  (const float4*)sr, (const float4*)st,
                                                  (const float4*)doff, (const float4*)toff,
                                                  rtw, mixb, mixs, ptb, x, Wout, (float*)d_out, N);
}

// Round 23
// 115.119 us; speedup vs baseline: 1.4077x; 1.0832x over previous
//
#include <hip/hip_runtime.h>
#include <math.h>

#define NH 4
#define NF 64
#define NM 32
#define NT 16  // nodes per block in k_projm
#define SC 32  // elements per thread in k_scan (supports N <= 32768)
#define AW 8   // waves per block in k_aggout

typedef __attribute__((ext_vector_type(8))) short bf16x8;
typedef __attribute__((ext_vector_type(4))) float f32x4;

// fast transcendentals (hardware v_exp/v_log/v_rcp); absmax margin 0.03 vs 0.105 absorbs ~1e-6
__device__ __forceinline__ float fexp(float v){ return __expf(v); }
__device__ __forceinline__ float softplusf(float v){ return fmaxf(v, 0.f) + __logf(1.f + __expf(-fabsf(v))); }
__device__ __forceinline__ float sigmoidf_(float v){ return __fdividef(1.f, 1.f + __expf(-v)); }
__device__ __forceinline__ unsigned short f2bf(float f) {
  unsigned u = __float_as_uint(f);
  u = u + 0x7FFFu + ((u >> 16) & 1u);   // round-to-nearest-even
  return (unsigned short)(u >> 16);
}
__device__ __forceinline__ float bflo(unsigned u){ return __uint_as_float(u << 16); }
__device__ __forceinline__ float bfhi(unsigned u){ return __uint_as_float(u & 0xFFFF0000u); }

// ---------------- K0: pack weights into MFMA fragments + zero deg ----------------
__global__ void k_pack(const float* __restrict__ Wp, const float* __restrict__ Wr,
                       const float* __restrict__ Wt,
                       const float* __restrict__ dW1, const float* __restrict__ tW1,
                       unsigned short* __restrict__ Wpk, int* __restrict__ z, int nz) {
  int t = blockIdx.x * blockDim.x + threadIdx.x;   // 8192 threads
  for (int i = t; i < nz; i += 8192) z[i] = 0;
  int lane = t & 63;
  int frag = t >> 6;   // 0..127
  if (frag >= 128) return;
  if (frag < 96) {
    int nb = frag & 3, kb = (frag >> 2) & 1, h = (frag >> 3) & 3, q = frag >> 5;
    const float* W = (q == 0 ? Wp : (q == 1 ? Wr : Wt));
    int col = nb * 16 + (lane & 15);
    int krow = kb * 32 + (lane >> 4) * 8;
    #pragma unroll
    for (int j = 0; j < 8; ++j)
      Wpk[((size_t)frag * 64 + lane) * 8 + j] = f2bf(W[(size_t)h * NF * NF + (krow + j) * NF + col]);
  } else {
    int f2 = frag - 96;
    int nb = f2 & 1, kb = (f2 >> 1) & 1, h = (f2 >> 2) & 3, p2 = f2 >> 4;
    const float* W = (p2 == 0 ? dW1 : tW1);
    int col = nb * 16 + (lane & 15);
    int krow = kb * 32 + (lane >> 4) * 8;
    #pragma unroll
    for (int j = 0; j < 8; ++j)
      Wpk[((size_t)frag * 64 + lane) * 8 + j] = f2bf(W[(size_t)h * NF * NM + (krow + j) * NM + col]);
  }
}

// ---------------- K0b: degree count (saves slot-within-receiver) ----------------
__global__ void k_count(const int* __restrict__ ei, int* __restrict__ deg,
                        int* __restrict__ slotw, int E) {
  int e = blockIdx.x * blockDim.x + threadIdx.x;
  if (e < E) slotw[e] = atomicAdd(&deg[ei[E + e]], 1);
}

// ---------------- K1: MFMA node pass (pt stored bf16, LDS-staged coalesced writes) ----------------
__global__ __launch_bounds__(256)
void k_projm(const float* __restrict__ x, const unsigned short* __restrict__ Wpk,
             const float* __restrict__ rsc, const float* __restrict__ tsc,
             const float* __restrict__ db1, const float* __restrict__ dw2, const float* __restrict__ db2,
             const float* __restrict__ tb1, const float* __restrict__ tw2, const float* __restrict__ tb2,
             const float* __restrict__ rdls, const float* __restrict__ rtb,
             unsigned short* __restrict__ ptb, float* __restrict__ sr, float* __restrict__ st,
             float* __restrict__ doff, float* __restrict__ toff, int N) {
  int n0 = blockIdx.x * NT;
  int tid = threadIdx.x;
  int h = tid >> 6, l = tid & 63;
  int lo = l & 15, hi = l >> 4;
  __shared__ __align__(16) unsigned short eps16[NH][16][72];  // bf16 ep, padded rows
  __shared__ __align__(16) unsigned short pts[NT][NF][8];     // staged rp/tp (16 KB)

  const bf16x8* W8 = (const bf16x8*)Wpk;

  bf16x8 a[2];
  {
    int nr = n0 + lo; if (nr >= N) nr = N - 1;
    const float* xr = x + (size_t)nr * NF + hi * 8;
    #pragma unroll
    for (int kb = 0; kb < 2; ++kb) {
      float4 v0 = *(const float4*)(xr + kb * 32);
      float4 v1 = *(const float4*)(xr + kb * 32 + 4);
      bf16x8 aa;
      aa[0] = (short)f2bf(v0.x); aa[1] = (short)f2bf(v0.y);
      aa[2] = (short)f2bf(v0.z); aa[3] = (short)f2bf(v0.w);
      aa[4] = (short)f2bf(v1.x); aa[5] = (short)f2bf(v1.y);
      aa[6] = (short)f2bf(v1.z); aa[7] = (short)f2bf(v1.w);
      a[kb] = aa;
    }
  }

  float srp[4] = {0.f,0.f,0.f,0.f}, stp[4] = {0.f,0.f,0.f,0.f};
  #pragma unroll
  for (int q = 0; q < 3; ++q) {
    #pragma unroll
    for (int nb = 0; nb < 4; ++nb) {
      f32x4 c = {0.f, 0.f, 0.f, 0.f};
      #pragma unroll
      for (int kb = 0; kb < 2; ++kb) {
        int frag = ((q * 4 + h) * 2 + kb) * 4 + nb;
        c = __builtin_amdgcn_mfma_f32_16x16x32_bf16(a[kb], W8[frag * 64 + l], c, 0, 0, 0);
      }
      int g = nb * 16 + lo;
      if (q == 0) {
        float rs = rsc[h * NF + g], ts = tsc[h * NF + g];
        #pragma unroll
        for (int r = 0; r < 4; ++r) {
          eps16[h][hi * 4 + r][g] = f2bf(c[r]);
          srp[r] += c[r] * rs;
          stp[r] += c[r] * ts;
        }
      } else {
        int row = (q - 1) * NH + h;
        #pragma unroll
        for (int r = 0; r < 4; ++r)
          pts[hi * 4 + r][g][row] = f2bf(c[r]);   // 2-way LDS bank alias: free
      }
    }
  }
  #pragma unroll
  for (int off = 1; off < 16; off <<= 1)
    #pragma unroll
    for (int r = 0; r < 4; ++r) { srp[r] += __shfl_xor(srp[r], off); stp[r] += __shfl_xor(stp[r], off); }
  if (lo == 0) {
    #pragma unroll
    for (int r = 0; r < 4; ++r) {
      int n = n0 + hi * 4 + r;
      if (n < N) { sr[n * NH + h] = srp[r]; st[n * NH + h] = stp[r]; }
    }
  }

  asm volatile("s_waitcnt lgkmcnt(0)" ::: "memory");
  bf16x8 ea[2];
  #pragma unroll
  for (int kb = 0; kb < 2; ++kb)
    ea[kb] = *(const bf16x8*)&eps16[h][lo][kb * 32 + hi * 8];

  float dpp[4] = {0.f,0.f,0.f,0.f}, tpp[4] = {0.f,0.f,0.f,0.f};
  #pragma unroll
  for (int p2 = 0; p2 < 2; ++p2) {
    #pragma unroll
    for (int nb = 0; nb < 2; ++nb) {
      f32x4 c = {0.f, 0.f, 0.f, 0.f};
      #pragma unroll
      for (int kb = 0; kb < 2; ++kb) {
        int frag = 96 + ((p2 * 4 + h) * 2 + kb) * 2 + nb;
        c = __builtin_amdgcn_mfma_f32_16x16x32_bf16(ea[kb], W8[frag * 64 + l], c, 0, 0, 0);
      }
      int m = nb * 16 + lo;
      float b1 = (p2 == 0 ? db1 : tb1)[h * NM + m];
      float w2 = (p2 == 0 ? dw2 : tw2)[h * NM + m];
      #pragma unroll
      for (int r = 0; r < 4; ++r) {
        float av = c[r] + b1;
        float sv = av * sigmoidf_(av) * w2;   // silu * w2
        if (p2 == 0) dpp[r] += sv; else tpp[r] += sv;
      }
    }
  }
  #pragma unroll
  for (int off = 1; off < 16; off <<= 1)
    #pragma unroll
    for (int r = 0; r < 4; ++r) { dpp[r] += __shfl_xor(dpp[r], off); tpp[r] += __shfl_xor(tpp[r], off); }
  if (lo == 0) {
    float dbase = db2[h] + softplusf(rdls[h]);
    float tbase = tb2[h] + rtb[h];
    #pragma unroll
    for (int r = 0; r < 4; ++r) {
      int n = n0 + hi * 4 + r;
      if (n < N) { doff[n * NH + h] = dpp[r] + dbase; toff[n * NH + h] = tpp[r] + tbase; }
    }
  }

  // coalesced ptb flush
  __syncthreads();
  for (int i = tid; i < NT * NF; i += 256) {
    int n = i >> 6, gg = i & 63;
    int gn = n0 + n;
    if (gn < N)
      *(uint4*)(ptb + ((size_t)gn * NF + gg) * 8) = *(const uint4*)&pts[n][gg][0];
  }
}

// ---------------- K2: exclusive prefix scan (thread-serial + one tree) ----------------
__global__ void k_scan(const int* __restrict__ deg, int* __restrict__ start, int N) {
  __shared__ int sums[1024];
  int tid = threadIdx.x;
  int base = tid * SC;
  int local[SC];
  int s = 0;
  #pragma unroll
  for (int j = 0; j < SC; ++j) {
    int i = base + j;
    int v = (i < N) ? deg[i] : 0;
    local[j] = s;
    s += v;
  }
  sums[tid] = s;
  __syncthreads();
  for (int off = 1; off < 1024; off <<= 1) {
    int t = (tid >= off) ? sums[tid - off] : 0;
    __syncthreads();
    sums[tid] += t;
    __syncthreads();
  }
  int tbase = (tid > 0) ? sums[tid - 1] : 0;
  #pragma unroll
  for (int j = 0; j < SC; ++j) {
    int i = base + j;
    if (i < N) start[i] = tbase + local[j];
  }
  if (tid == 1023) start[N] = sums[1023];
}

// ---------------- K3: CSR fill (no atomics; int2 combined store) ----------------
__global__ void k_fill(const int* __restrict__ ei, const float* __restrict__ elen,
                       const int* __restrict__ start, const int* __restrict__ slotw,
                       int2* __restrict__ cse, int E) {
  int e = blockIdx.x * blockDim.x + threadIdx.x;
  if (e >= E) return;
  int r = ei[E + e];
  int slot = start[r] + slotw[e];
  cse[slot] = make_int2(ei[e], __float_as_int(elen[e]));
}

// ---------------- K4: fused logits + softmax + gather-aggregate + Wout + residual ----------------
__device__ __forceinline__ float dot8(const float* cf, uint4 uv) {
  return cf[0] * bflo(uv.x) + cf[1] * bfhi(uv.x)
       + cf[2] * bflo(uv.y) + cf[3] * bfhi(uv.y)
       + cf[4] * bflo(uv.z) + cf[5] * bfhi(uv.z)
       + cf[6] * bflo(uv.w) + cf[7] * bfhi(uv.w);
}

__global__ __launch_bounds__(512)
void k_aggout(const int* __restrict__ start, const int2* __restrict__ cse,
              const float4* __restrict__ sr4, const float4* __restrict__ st4,
              const float4* __restrict__ doff4, const float4* __restrict__ toff4,
              const float* __restrict__ rtw, const float* __restrict__ mixb, const float* __restrict__ mixs,
              const unsigned short* __restrict__ ptb, const float* __restrict__ x,
              const float* __restrict__ Wout, float* __restrict__ out, int N) {
  __shared__ float wout_s[NF * NF];
  __shared__ float coef_s[AW][64][8];
  __shared__ int   snd_s[AW][64];
  __shared__ float am_s[AW][NF];
  int tid = threadIdx.x;
  {
    const float4* w4 = (const float4*)Wout;
    float4* s4 = (float4*)wout_s;
    for (int i = tid; i < NF * NF / 4; i += 512) s4[i] = w4[i];
  }
  __syncthreads();   // only block-wide barrier; everything after is wave-local
  int w = tid >> 6, g = tid & 63;
  int n = blockIdx.x * AW + w;
  if (n >= N) return;
  int i0 = start[n], i1 = start[n + 1];
  int deg = i1 - i0;

  float sc1[NH] = {0.f,0.f,0.f,0.f}, sc2[NH] = {0.f,0.f,0.f,0.f};
  float acc0 = 0.f, acc1 = 0.f, acc2 = 0.f, acc3 = 0.f;

  if (deg <= 64) {
    // ---------- fast path: lane = (edge, head); up to 4 chunks of 16 edges ----------
    int eL = g >> 2;          // edge within chunk (0..15)
    int hh = g & 3;           // head
    const float* srf = (const float*)sr4;
    const float* stf = (const float*)st4;
    float srn_h = srf[n * NH + hh], stn_h = stf[n * NH + hh];
    float dof_h = ((const float*)doff4)[n * NH + hh];
    float tof_h = ((const float*)toff4)[n * NH + hh];
    float rtw_h = rtw[hh], mb_h = mixb[hh], ms_h = mixs[hh];

    float rl[4], tl[4], gvc[4];
    int   sE[4];
    #pragma unroll
    for (int c = 0; c < 4; ++c) {
      int eidx = c * 16 + eL;
      bool act = eidx < deg;
      int2 sv = act ? cse[i0 + eidx] : make_int2(0, 0);
      sE[c] = sv.x;
      float len = __int_as_float(sv.y);
      float temp = softplusf(tof_h + rtw_h * len);
      float srs = srf[sv.x * NH + hh];
      float sts = stf[sv.x * NH + hh];
      rl[c] = act ? __fdividef(srs - srn_h - dof_h * len, temp + 1e-4f) : -1e30f;
      tl[c] = act ? (sts - stn_h) : -1e30f;
      gvc[c] = sigmoidf_(mb_h + ms_h * len);
    }
    float rmx = fmaxf(fmaxf(rl[0], rl[1]), fmaxf(rl[2], rl[3]));
    float tmx = fmaxf(fmaxf(tl[0], tl[1]), fmaxf(tl[2], tl[3]));
    #pragma unroll
    for (int off = 4; off < 64; off <<= 1) {
      rmx = fmaxf(rmx, __shfl_xor(rmx, off));
      tmx = fmaxf(tmx, __shfl_xor(tmx, off));
    }
    float er[4], et[4], esum = 0.f, tsum = 0.f;
    #pragma unroll
    for (int c = 0; c < 4; ++c) {
      bool act = (c * 16 + eL) < deg;
      er[c] = act ? fexp(rl[c] - rmx) : 0.f;
      et[c] = act ? fexp(tl[c] - tmx) : 0.f;
      esum += er[c]; tsum += et[c];
    }
    #pragma unroll
    for (int off = 4; off < 64; off <<= 1) {
      esum += __shfl_xor(esum, off);
      tsum += __shfl_xor(tsum, off);
    }
    float rinv = __fdividef(1.f, esum + 1e-9f);
    float tinv = __fdividef(1.f, tsum + 1e-9f);
    float sc1o = 0.f, sc2o = 0.f;
    #pragma unroll
    for (int c = 0; c < 4; ++c) {
      float ar = er[c] * rinv, at = et[c] * tinv;
      float gg = gvc[c];
      float ba = gg * ar + (1.f - gg) * at;
      float c1 = ba * gg, c2 = ba * (1.f - gg);
      sc1o += c1; sc2o += c2;
      int e = c * 16 + eL;
      coef_s[w][e][hh] = c1; coef_s[w][e][4 + hh] = c2;
      if (hh == 0) snd_s[w][e] = sE[c];
    }
    // scatter own-head partials into the 4-vector (static index + predication)
    #pragma unroll
    for (int h2 = 0; h2 < NH; ++h2) {
      sc1[h2] = (h2 == hh) ? sc1o : 0.f;
      sc2[h2] = (h2 == hh) ? sc2o : 0.f;
    }
    // gather (lane = feature, 4-way ILP)
    int j = 0;
    for (; j + 4 <= deg; j += 4) {
      uint4 u0 = *(const uint4*)(ptb + ((size_t)snd_s[w][j]     * NF + g) * 8);
      uint4 u1 = *(const uint4*)(ptb + ((size_t)snd_s[w][j + 1] * NF + g) * 8);
      uint4 u2 = *(const uint4*)(ptb + ((size_t)snd_s[w][j + 2] * NF + g) * 8);
      uint4 u3 = *(const uint4*)(ptb + ((size_t)snd_s[w][j + 3] * NF + g) * 8);
      acc0 += dot8(coef_s[w][j],     u0);
      acc1 += dot8(coef_s[w][j + 1], u1);
      acc2 += dot8(coef_s[w][j + 2], u2);
      acc3 += dot8(coef_s[w][j + 3], u3);
    }
    for (; j < deg; ++j) {
      uint4 u0 = *(const uint4*)(ptb + ((size_t)snd_s[w][j] * NF + g) * 8);
      acc0 += dot8(coef_s[w][j], u0);
    }
  } else {
    // ---------- slow path (deg > 64): chunked 3 passes, logits recomputed ----------
    float4 srn = sr4[n], stn = st4[n], dofn = doff4[n], tofn = toff4[n];
    const float* srnp = (const float*)&srn; const float* stnp = (const float*)&stn;
    const float* dofnp = (const float*)&dofn; const float* tofnp = (const float*)&tofn;
    float rtwv[NH], mbv[NH], msv[NH];
    #pragma unroll
    for (int h = 0; h < NH; ++h) { rtwv[h] = rtw[h]; mbv[h] = mixb[h]; msv[h] = mixs[h]; }
    float rm[NH], tm[NH];
    float rs_[NH] = {0.f,0.f,0.f,0.f}, ts_[NH] = {0.f,0.f,0.f,0.f};
    #pragma unroll
    for (int h = 0; h < NH; ++h) { rm[h] = -1e30f; tm[h] = -1e30f; }
    for (int base = i0; base < i1; base += 64) {
      int i = base + g; bool act = (i < i1);
      int2 sv = act ? cse[i] : make_int2(0, 0);
      int s = sv.x; float len = __int_as_float(sv.y);
      float4 as4 = sr4[s], cs4 = st4[s];
      const float* asp = (const float*)&as4; const float* csp = (const float*)&cs4;
      #pragma unroll
      for (int h = 0; h < NH; ++h) {
        float temp = softplusf(tofnp[h] + rtwv[h] * len);
        float rl = act ? __fdividef(asp[h] - srnp[h] - dofnp[h] * len, temp + 1e-4f) : -1e30f;
        float tl = act ? (csp[h] - stnp[h]) : -1e30f;
        rm[h] = fmaxf(rm[h], rl); tm[h] = fmaxf(tm[h], tl);
      }
    }
    #pragma unroll
    for (int off = 32; off; off >>= 1)
      #pragma unroll
      for (int h = 0; h < NH; ++h) {
        rm[h] = fmaxf(rm[h], __shfl_xor(rm[h], off));
        tm[h] = fmaxf(tm[h], __shfl_xor(tm[h], off));
      }
    for (int base = i0; base < i1; base += 64) {
      int i = base + g; bool act = (i < i1);
      int2 sv = act ? cse[i] : make_int2(0, 0);
      int s = sv.x; float len = __int_as_float(sv.y);
      float4 as4 = sr4[s], cs4 = st4[s];
      const float* asp = (const float*)&as4; const float* csp = (const float*)&cs4;
      #pragma unroll
      for (int h = 0; h < NH; ++h) {
        float temp = softplusf(tofnp[h] + rtwv[h] * len);
        float rl = act ? __fdividef(asp[h] - srnp[h] - dofnp[h] * len, temp + 1e-4f) : -1e30f;
        float tl = act ? (csp[h] - stnp[h]) : -1e30f;
        rs_[h] += act ? fexp(rl - rm[h]) : 0.f;
        ts_[h] += act ? fexp(tl - tm[h]) : 0.f;
      }
    }
    #pragma unroll
    for (int off = 32; off; off >>= 1)
      #pragma unroll
      for (int h = 0; h < NH; ++h) { rs_[h] += __shfl_xor(rs_[h], off); ts_[h] += __shfl_xor(ts_[h], off); }
    #pragma unroll
    for (int h = 0; h < NH; ++h) { rs_[h] = __fdividef(1.f, rs_[h] + 1e-9f); ts_[h] = __fdividef(1.f, ts_[h] + 1e-9f); }
    for (int base = i0; base < i1; base += 64) {
      int i = base + g; bool act = (i < i1);
      int2 sv = act ? cse[i] : make_int2(0, 0);
      int s = sv.x; float len = __int_as_float(sv.y);
      float4 as4 = sr4[s], cs4 = st4[s];
      const float* asp = (const float*)&as4; const float* csp = (const float*)&cs4;
      #pragma unroll
      for (int h = 0; h < NH; ++h) {
        float temp = softplusf(tofnp[h] + rtwv[h] * len);
        float rl = act ? __fdividef(asp[h] - srnp[h] - dofnp[h] * len, temp + 1e-4f) : -1e30f;
        float tl = act ? (csp[h] - stnp[h]) : -1e30f;
        float gg = sigmoidf_(mbv[h] + msv[h] * len);
        float ar = (act ? fexp(rl - rm[h]) : 0.f) * rs_[h];
        float at = (act ? fexp(tl - tm[h]) : 0.f) * ts_[h];
        float ba = gg * ar + (1.f - gg) * at;
        float c1 = ba * gg, c2 = ba * (1.f - gg);
        coef_s[w][g][h] = c1; coef_s[w][g][4 + h] = c2;
        sc1[h] += c1; sc2[h] += c2;
      }
      snd_s[w][g] = s;
      int cnt = min(64, i1 - base);
      int j = 0;
      for (; j + 4 <= cnt; j += 4) {
        uint4 u0 = *(const uint4*)(ptb + ((size_t)snd_s[w][j]     * NF + g) * 8);
        uint4 u1 = *(const uint4*)(ptb + ((size_t)snd_s[w][j + 1] * NF + g) * 8);
        uint4 u2 = *(const uint4*)(ptb + ((size_t)snd_s[w][j + 2] * NF + g) * 8);
        uint4 u3 = *(const uint4*)(ptb + ((size_t)snd_s[w][j + 3] * NF + g) * 8);
        acc0 += dot8(coef_s[w][j],     u0);
        acc1 += dot8(coef_s[w][j + 1], u1);
        acc2 += dot8(coef_s[w][j + 2], u2);
        acc3 += dot8(coef_s[w][j + 3], u3);
      }
      for (; j < cnt; ++j) {
        uint4 u0 = *(const uint4*)(ptb + ((size_t)snd_s[w][j] * NF + g) * 8);
        acc0 += dot8(coef_s[w][j], u0);
      }
    }
  }

  float acc = (acc0 + acc1) + (acc2 + acc3);
  #pragma unroll
  for (int off = 32; off; off >>= 1)
    #pragma unroll
    for (int h = 0; h < NH; ++h) { sc1[h] += __shfl_xor(sc1[h], off); sc2[h] += __shfl_xor(sc2[h], off); }

  {
    uint4 uv = *(const uint4*)(ptb + ((size_t)n * NF + g) * 8);
    acc -= sc1[0] * bflo(uv.x) + sc1[1] * bfhi(uv.x)
         + sc1[2] * bflo(uv.y) + sc1[3] * bfhi(uv.y)
         + sc2[0] * bflo(uv.z) + sc2[1] * bfhi(uv.z)
         + sc2[2] * bflo(uv.w) + sc2[3] * bfhi(uv.w);
  }
  acc *= (1.f / NH);

  am_s[w][g] = acc;   // wave-local LDS; no block barrier needed
  float o = x[(size_t)n * NF + g];
  #pragma unroll 8
  for (int f = 0; f < NF; ++f) o += am_s[w][f] * wout_s[f * NF + g];
  out[(size_t)n * NF + g] = o;
}

extern "C" void kernel_launch(void* const* d_in, const int* in_sizes, int n_in,
                              void* d_out, int out_size, void* d_ws, size_t ws_size,
                              hipStream_t stream) {
  const float* x    = (const float*)d_in[0];
  const int*   ei   = (const int*)d_in[1];
  // d_in[2] = edge_vec, unused by the reference
  const float* elen = (const float*)d_in[3];
  const float* Wp   = (const float*)d_in[4];
  const float* Wr   = (const float*)d_in[5];
  const float* Wt   = (const float*)d_in[6];
  const float* rsc  = (const float*)d_in[7];
  const float* tsc  = (const float*)d_in[8];
  const float* rdls = (const float*)d_in[9];
  const float* rtb  = (const float*)d_in[10];
  const float* rtw  = (const float*)d_in[11];
  const float* mixb = (const float*)d_in[12];
  const float* mixs = (const float*)d_in[13];
  const float* dW1  = (const float*)d_in[14];
  const float* db1  = (const float*)d_in[15];
  const float* dw2  = (const float*)d_in[16];
  const float* db2  = (const float*)d_in[17];
  const float* tW1  = (const float*)d_in[18];
  const float* tb1  = (const float*)d_in[19];
  const float* tw2  = (const float*)d_in[20];
  const float* tb2  = (const float*)d_in[21];
  const float* Wout = (const float*)d_in[22];

  int N = in_sizes[0] / NF;
  int E = in_sizes[3];

  float* p = (float*)d_ws;
  unsigned short* Wpk = (unsigned short*)p; p += 32768;  // 128 frag x 64 lanes x 8 bf16 = 131072 B
  unsigned short* ptb = (unsigned short*)p; p += (size_t)N * NF * 8 / 2;  // [n][g][8] bf16
  float* sr   = p; p += (size_t)N * NH;
  float* st   = p; p += (size_t)N * NH;
  float* doff = p; p += (size_t)N * NH;
  float* toff = p; p += (size_t)N * NH;
  int2* cse   = (int2*)p; p += (size_t)2 * E;  // CSR-ordered {sender, elen}
  int* slotw  = (int*)p; p += E;               // slot-within-receiver per edge
  int* deg    = (int*)p; p += N;
  int* startp = (int*)p; p += N + 1;

  // K0: pack weights + zero deg
  k_pack<<<32, 256, 0, stream>>>(Wp, Wr, Wt, dW1, tW1, Wpk, deg, N);
  // K0b: degree count (+slot within receiver)
  k_count<<<(E + 255) / 256, 256, 0, stream>>>(ei, deg, slotw, E);
  // K1: MFMA node pass
  k_projm<<<(N + NT - 1) / NT, 256, 0, stream>>>(x, Wpk, rsc, tsc, db1, dw2, db2,
                                                 tb1, tw2, tb2, rdls, rtb,
                                                 ptb, sr, st, doff, toff, N);
  // K2: scan degrees -> CSR starts
  k_scan<<<1, 1024, 0, stream>>>(deg, startp, N);
  // K3: CSR fill (no atomics)
  k_fill<<<(E + 255) / 256, 256, 0, stream>>>(ei, elen, startp, slotw, cse, E);
  // K4: fused logits + softmax + aggregate + output
  k_aggout<<<(N + AW - 1) / AW, 512, 0, stream>>>(startp, cse,
                                                  (const float4*)sr, (const float4*)st,
                                                  (const float4*)doff, (const float4*)toff,
                                                  rtw, mixb, mixs, ptb, x, Wout, (float*)d_out, N);
}

// Round 24
// 114.337 us; speedup vs baseline: 1.4174x; 1.0068x over previous
//
#include <hip/hip_runtime.h>
#include <math.h>

#define NH 4
#define NF 64
#define NM 32
#define NT 16  // nodes per block in k_projm
#define SC 32  // elements per thread in k_scan (supports N <= 32768)
#define AW 8   // waves per block in k_aggout

typedef __attribute__((ext_vector_type(8))) short bf16x8;
typedef __attribute__((ext_vector_type(4))) float f32x4;

// fast transcendentals (hardware v_exp/v_log/v_rcp); absmax margin 0.03 vs 0.105 absorbs ~1e-6
__device__ __forceinline__ float fexp(float v){ return __expf(v); }
__device__ __forceinline__ float softplusf(float v){ return fmaxf(v, 0.f) + __logf(1.f + __expf(-fabsf(v))); }
__device__ __forceinline__ float sigmoidf_(float v){ return __fdividef(1.f, 1.f + __expf(-v)); }
__device__ __forceinline__ unsigned short f2bf(float f) {
  unsigned u = __float_as_uint(f);
  u = u + 0x7FFFu + ((u >> 16) & 1u);   // round-to-nearest-even
  return (unsigned short)(u >> 16);
}
__device__ __forceinline__ float bflo(unsigned u){ return __uint_as_float(u << 16); }
__device__ __forceinline__ float bfhi(unsigned u){ return __uint_as_float(u & 0xFFFF0000u); }

// ---------------- K0: pack weights into MFMA fragments + zero deg ----------------
__global__ void k_pack(const float* __restrict__ Wp, const float* __restrict__ Wr,
                       const float* __restrict__ Wt,
                       const float* __restrict__ dW1, const float* __restrict__ tW1,
                       unsigned short* __restrict__ Wpk, int* __restrict__ z, int nz) {
  int t = blockIdx.x * blockDim.x + threadIdx.x;   // 8192 threads
  for (int i = t; i < nz; i += 8192) z[i] = 0;
  int lane = t & 63;
  int frag = t >> 6;   // 0..127
  if (frag >= 128) return;
  if (frag < 96) {
    int nb = frag & 3, kb = (frag >> 2) & 1, h = (frag >> 3) & 3, q = frag >> 5;
    const float* W = (q == 0 ? Wp : (q == 1 ? Wr : Wt));
    int col = nb * 16 + (lane & 15);
    int krow = kb * 32 + (lane >> 4) * 8;
    #pragma unroll
    for (int j = 0; j < 8; ++j)
      Wpk[((size_t)frag * 64 + lane) * 8 + j] = f2bf(W[(size_t)h * NF * NF + (krow + j) * NF + col]);
  } else {
    int f2 = frag - 96;
    int nb = f2 & 1, kb = (f2 >> 1) & 1, h = (f2 >> 2) & 3, p2 = f2 >> 4;
    const float* W = (p2 == 0 ? dW1 : tW1);
    int col = nb * 16 + (lane & 15);
    int krow = kb * 32 + (lane >> 4) * 8;
    #pragma unroll
    for (int j = 0; j < 8; ++j)
      Wpk[((size_t)frag * 64 + lane) * 8 + j] = f2bf(W[(size_t)h * NF * NM + (krow + j) * NM + col]);
  }
}

// ---------------- K1: MFMA node pass + edge degree count (fused) ----------------
__global__ __launch_bounds__(256)
void k_projm(const float* __restrict__ x, const unsigned short* __restrict__ Wpk,
             const float* __restrict__ rsc, const float* __restrict__ tsc,
             const float* __restrict__ db1, const float* __restrict__ dw2, const float* __restrict__ db2,
             const float* __restrict__ tb1, const float* __restrict__ tw2, const float* __restrict__ tb2,
             const float* __restrict__ rdls, const float* __restrict__ rtb,
             unsigned short* __restrict__ ptb, float* __restrict__ sr, float* __restrict__ st,
             float* __restrict__ doff, float* __restrict__ toff,
             const int* __restrict__ ei, int* __restrict__ deg, int* __restrict__ slotw,
             int N, int E) {
  int n0 = blockIdx.x * NT;
  int tid = threadIdx.x;
  int h = tid >> 6, l = tid & 63;
  int lo = l & 15, hi = l >> 4;
  __shared__ __align__(16) unsigned short eps16[NH][16][72];  // bf16 ep, padded rows
  __shared__ __align__(16) unsigned short pts[NT][NF][8];     // staged rp/tp (16 KB)

  const bf16x8* W8 = (const bf16x8*)Wpk;

  bf16x8 a[2];
  {
    int nr = n0 + lo; if (nr >= N) nr = N - 1;
    const float* xr = x + (size_t)nr * NF + hi * 8;
    #pragma unroll
    for (int kb = 0; kb < 2; ++kb) {
      float4 v0 = *(const float4*)(xr + kb * 32);
      float4 v1 = *(const float4*)(xr + kb * 32 + 4);
      bf16x8 aa;
      aa[0] = (short)f2bf(v0.x); aa[1] = (short)f2bf(v0.y);
      aa[2] = (short)f2bf(v0.z); aa[3] = (short)f2bf(v0.w);
      aa[4] = (short)f2bf(v1.x); aa[5] = (short)f2bf(v1.y);
      aa[6] = (short)f2bf(v1.z); aa[7] = (short)f2bf(v1.w);
      a[kb] = aa;
    }
  }

  float srp[4] = {0.f,0.f,0.f,0.f}, stp[4] = {0.f,0.f,0.f,0.f};
  #pragma unroll
  for (int q = 0; q < 3; ++q) {
    #pragma unroll
    for (int nb = 0; nb < 4; ++nb) {
      f32x4 c = {0.f, 0.f, 0.f, 0.f};
      #pragma unroll
      for (int kb = 0; kb < 2; ++kb) {
        int frag = ((q * 4 + h) * 2 + kb) * 4 + nb;
        c = __builtin_amdgcn_mfma_f32_16x16x32_bf16(a[kb], W8[frag * 64 + l], c, 0, 0, 0);
      }
      int g = nb * 16 + lo;
      if (q == 0) {
        float rs = rsc[h * NF + g], ts = tsc[h * NF + g];
        #pragma unroll
        for (int r = 0; r < 4; ++r) {
          eps16[h][hi * 4 + r][g] = f2bf(c[r]);
          srp[r] += c[r] * rs;
          stp[r] += c[r] * ts;
        }
      } else {
        int row = (q - 1) * NH + h;
        #pragma unroll
        for (int r = 0; r < 4; ++r)
          pts[hi * 4 + r][g][row] = f2bf(c[r]);   // 2-way LDS bank alias: free
      }
    }
  }
  #pragma unroll
  for (int off = 1; off < 16; off <<= 1)
    #pragma unroll
    for (int r = 0; r < 4; ++r) { srp[r] += __shfl_xor(srp[r], off); stp[r] += __shfl_xor(stp[r], off); }
  if (lo == 0) {
    #pragma unroll
    for (int r = 0; r < 4; ++r) {
      int n = n0 + hi * 4 + r;
      if (n < N) { sr[n * NH + h] = srp[r]; st[n * NH + h] = stp[r]; }
    }
  }

  asm volatile("s_waitcnt lgkmcnt(0)" ::: "memory");
  bf16x8 ea[2];
  #pragma unroll
  for (int kb = 0; kb < 2; ++kb)
    ea[kb] = *(const bf16x8*)&eps16[h][lo][kb * 32 + hi * 8];

  float dpp[4] = {0.f,0.f,0.f,0.f}, tpp[4] = {0.f,0.f,0.f,0.f};
  #pragma unroll
  for (int p2 = 0; p2 < 2; ++p2) {
    #pragma unroll
    for (int nb = 0; nb < 2; ++nb) {
      f32x4 c = {0.f, 0.f, 0.f, 0.f};
      #pragma unroll
      for (int kb = 0; kb < 2; ++kb) {
        int frag = 96 + ((p2 * 4 + h) * 2 + kb) * 2 + nb;
        c = __builtin_amdgcn_mfma_f32_16x16x32_bf16(ea[kb], W8[frag * 64 + l], c, 0, 0, 0);
      }
      int m = nb * 16 + lo;
      float b1 = (p2 == 0 ? db1 : tb1)[h * NM + m];
      float w2 = (p2 == 0 ? dw2 : tw2)[h * NM + m];
      #pragma unroll
      for (int r = 0; r < 4; ++r) {
        float av = c[r] + b1;
        float sv = av * sigmoidf_(av) * w2;   // silu * w2
        if (p2 == 0) dpp[r] += sv; else tpp[r] += sv;
      }
    }
  }
  #pragma unroll
  for (int off = 1; off < 16; off <<= 1)
    #pragma unroll
    for (int r = 0; r < 4; ++r) { dpp[r] += __shfl_xor(dpp[r], off); tpp[r] += __shfl_xor(tpp[r], off); }
  if (lo == 0) {
    float dbase = db2[h] + softplusf(rdls[h]);
    float tbase = tb2[h] + rtb[h];
    #pragma unroll
    for (int r = 0; r < 4; ++r) {
      int n = n0 + hi * 4 + r;
      if (n < N) { doff[n * NH + h] = dpp[r] + dbase; toff[n * NH + h] = tpp[r] + tbase; }
    }
  }

  // coalesced ptb flush
  __syncthreads();
  for (int i = tid; i < NT * NF; i += 256) {
    int n = i >> 6, gg = i & 63;
    int gn = n0 + n;
    if (gn < N)
      *(uint4*)(ptb + ((size_t)gn * NF + gg) * 8) = *(const uint4*)&pts[n][gg][0];
  }

  // fused edge degree count (deg zeroed by k_pack, which ran before)
  for (int e = blockIdx.x * 256 + tid; e < E; e += gridDim.x * 256)
    slotw[e] = atomicAdd(&deg[ei[E + e]], 1);
}

// ---------------- K2: exclusive prefix scan (thread-serial + one tree) ----------------
__global__ void k_scan(const int* __restrict__ deg, int* __restrict__ start, int N) {
  __shared__ int sums[1024];
  int tid = threadIdx.x;
  int base = tid * SC;
  int local[SC];
  int s = 0;
  #pragma unroll
  for (int j = 0; j < SC; ++j) {
    int i = base + j;
    int v = (i < N) ? deg[i] : 0;
    local[j] = s;
    s += v;
  }
  sums[tid] = s;
  __syncthreads();
  for (int off = 1; off < 1024; off <<= 1) {
    int t = (tid >= off) ? sums[tid - off] : 0;
    __syncthreads();
    sums[tid] += t;
    __syncthreads();
  }
  int tbase = (tid > 0) ? sums[tid - 1] : 0;
  #pragma unroll
  for (int j = 0; j < SC; ++j) {
    int i = base + j;
    if (i < N) start[i] = tbase + local[j];
  }
  if (tid == 1023) start[N] = sums[1023];
}

// ---------------- K3: CSR fill (no atomics; int2 combined store) ----------------
__global__ void k_fill(const int* __restrict__ ei, const float* __restrict__ elen,
                       const int* __restrict__ start, const int* __restrict__ slotw,
                       int2* __restrict__ cse, int E) {
  int e = blockIdx.x * blockDim.x + threadIdx.x;
  if (e >= E) return;
  int r = ei[E + e];
  int slot = start[r] + slotw[e];
  cse[slot] = make_int2(ei[e], __float_as_int(elen[e]));
}

// ---------------- K4: fused logits + softmax + gather-aggregate + Wout + residual ----------------
__device__ __forceinline__ float dot8(const float* cf, uint4 uv) {
  return cf[0] * bflo(uv.x) + cf[1] * bfhi(uv.x)
       + cf[2] * bflo(uv.y) + cf[3] * bfhi(uv.y)
       + cf[4] * bflo(uv.z) + cf[5] * bfhi(uv.z)
       + cf[6] * bflo(uv.w) + cf[7] * bfhi(uv.w);
}

__global__ __launch_bounds__(512)
void k_aggout(const int* __restrict__ start, const int2* __restrict__ cse,
              const float4* __restrict__ sr4, const float4* __restrict__ st4,
              const float4* __restrict__ doff4, const float4* __restrict__ toff4,
              const float* __restrict__ rtw, const float* __restrict__ mixb, const float* __restrict__ mixs,
              const unsigned short* __restrict__ ptb, const float* __restrict__ x,
              const float* __restrict__ Wout, float* __restrict__ out, int N) {
  __shared__ float wout_s[NF * NF];
  __shared__ float coef_s[AW][64][8];
  __shared__ int   snd_s[AW][64];
  __shared__ float am_s[AW][NF];
  int tid = threadIdx.x;
  {
    const float4* w4 = (const float4*)Wout;
    float4* s4 = (float4*)wout_s;
    for (int i = tid; i < NF * NF / 4; i += 512) s4[i] = w4[i];
  }
  __syncthreads();   // only block-wide barrier; everything after is wave-local
  int w = tid >> 6, g = tid & 63;
  int n = blockIdx.x * AW + w;
  if (n >= N) return;
  int i0 = start[n], i1 = start[n + 1];
  int deg = i1 - i0;

  float sc1[NH] = {0.f,0.f,0.f,0.f}, sc2[NH] = {0.f,0.f,0.f,0.f};
  float acc0 = 0.f, acc1 = 0.f, acc2 = 0.f, acc3 = 0.f;

  if (deg <= 64) {
    // ---------- fast path: lane = (edge, head); up to 4 chunks of 16 edges ----------
    int eL = g >> 2;          // edge within chunk (0..15)
    int hh = g & 3;           // head
    const float* srf = (const float*)sr4;
    const float* stf = (const float*)st4;
    float srn_h = srf[n * NH + hh], stn_h = stf[n * NH + hh];
    float dof_h = ((const float*)doff4)[n * NH + hh];
    float tof_h = ((const float*)toff4)[n * NH + hh];
    float rtw_h = rtw[hh], mb_h = mixb[hh], ms_h = mixs[hh];

    float rl[4], tl[4], gvc[4];
    int   sE[4];
    #pragma unroll
    for (int c = 0; c < 4; ++c) {
      int eidx = c * 16 + eL;
      bool act = eidx < deg;
      int2 sv = act ? cse[i0 + eidx] : make_int2(0, 0);
      sE[c] = sv.x;
      float len = __int_as_float(sv.y);
      float temp = softplusf(tof_h + rtw_h * len);
      float srs = srf[sv.x * NH + hh];
      float sts = stf[sv.x * NH + hh];
      rl[c] = act ? __fdividef(srs - srn_h - dof_h * len, temp + 1e-4f) : -1e30f;
      tl[c] = act ? (sts - stn_h) : -1e30f;
      gvc[c] = sigmoidf_(mb_h + ms_h * len);
    }
    float rmx = fmaxf(fmaxf(rl[0], rl[1]), fmaxf(rl[2], rl[3]));
    float tmx = fmaxf(fmaxf(tl[0], tl[1]), fmaxf(tl[2], tl[3]));
    #pragma unroll
    for (int off = 4; off < 64; off <<= 1) {
      rmx = fmaxf(rmx, __shfl_xor(rmx, off));
      tmx = fmaxf(tmx, __shfl_xor(tmx, off));
    }
    float er[4], et[4], esum = 0.f, tsum = 0.f;
    #pragma unroll
    for (int c = 0; c < 4; ++c) {
      bool act = (c * 16 + eL) < deg;
      er[c] = act ? fexp(rl[c] - rmx) : 0.f;
      et[c] = act ? fexp(tl[c] - tmx) : 0.f;
      esum += er[c]; tsum += et[c];
    }
    #pragma unroll
    for (int off = 4; off < 64; off <<= 1) {
      esum += __shfl_xor(esum, off);
      tsum += __shfl_xor(tsum, off);
    }
    float rinv = __fdividef(1.f, esum + 1e-9f);
    float tinv = __fdividef(1.f, tsum + 1e-9f);
    float sc1o = 0.f, sc2o = 0.f;
    #pragma unroll
    for (int c = 0; c < 4; ++c) {
      float ar = er[c] * rinv, at = et[c] * tinv;
      float gg = gvc[c];
      float ba = gg * ar + (1.f - gg) * at;
      float c1 = ba * gg, c2 = ba * (1.f - gg);
      sc1o += c1; sc2o += c2;
      int e = c * 16 + eL;
      coef_s[w][e][hh] = c1; coef_s[w][e][4 + hh] = c2;
      if (hh == 0) snd_s[w][e] = sE[c];
    }
    #pragma unroll
    for (int h2 = 0; h2 < NH; ++h2) {
      sc1[h2] = (h2 == hh) ? sc1o : 0.f;
      sc2[h2] = (h2 == hh) ? sc2o : 0.f;
    }
    // gather (lane = feature, 8-way ILP)
    int j = 0;
    for (; j + 8 <= deg; j += 8) {
      uint4 u0 = *(const uint4*)(ptb + ((size_t)snd_s[w][j]     * NF + g) * 8);
      uint4 u1 = *(const uint4*)(ptb + ((size_t)snd_s[w][j + 1] * NF + g) * 8);
      uint4 u2 = *(const uint4*)(ptb + ((size_t)snd_s[w][j + 2] * NF + g) * 8);
      uint4 u3 = *(const uint4*)(ptb + ((size_t)snd_s[w][j + 3] * NF + g) * 8);
      uint4 u4 = *(const uint4*)(ptb + ((size_t)snd_s[w][j + 4] * NF + g) * 8);
      uint4 u5 = *(const uint4*)(ptb + ((size_t)snd_s[w][j + 5] * NF + g) * 8);
      uint4 u6 = *(const uint4*)(ptb + ((size_t)snd_s[w][j + 6] * NF + g) * 8);
      uint4 u7 = *(const uint4*)(ptb + ((size_t)snd_s[w][j + 7] * NF + g) * 8);
      acc0 += dot8(coef_s[w][j],     u0);
      acc1 += dot8(coef_s[w][j + 1], u1);
      acc2 += dot8(coef_s[w][j + 2], u2);
      acc3 += dot8(coef_s[w][j + 3], u3);
      acc0 += dot8(coef_s[w][j + 4], u4);
      acc1 += dot8(coef_s[w][j + 5], u5);
      acc2 += dot8(coef_s[w][j + 6], u6);
      acc3 += dot8(coef_s[w][j + 7], u7);
    }
    for (; j + 4 <= deg; j += 4) {
      uint4 u0 = *(const uint4*)(ptb + ((size_t)snd_s[w][j]     * NF + g) * 8);
      uint4 u1 = *(const uint4*)(ptb + ((size_t)snd_s[w][j + 1] * NF + g) * 8);
      uint4 u2 = *(const uint4*)(ptb + ((size_t)snd_s[w][j + 2] * NF + g) * 8);
      uint4 u3 = *(const uint4*)(ptb + ((size_t)snd_s[w][j + 3] * NF + g) * 8);
      acc0 += dot8(coef_s[w][j],     u0);
      acc1 += dot8(coef_s[w][j + 1], u1);
      acc2 += dot8(coef_s[w][j + 2], u2);
      acc3 += dot8(coef_s[w][j + 3], u3);
    }
    for (; j < deg; ++j) {
      uint4 u0 = *(const uint4*)(ptb + ((size_t)snd_s[w][j] * NF + g) * 8);
      acc0 += dot8(coef_s[w][j], u0);
    }
  } else {
    // ---------- slow path (deg > 64): chunked 3 passes, logits recomputed ----------
    float4 srn = sr4[n], stn = st4[n], dofn = doff4[n], tofn = toff4[n];
    const float* srnp = (const float*)&srn; const float* stnp = (const float*)&stn;
    const float* dofnp = (const float*)&dofn; const float* tofnp = (const float*)&tofn;
    float rtwv[NH], mbv[NH], msv[NH];
    #pragma unroll
    for (int h = 0; h < NH; ++h) { rtwv[h] = rtw[h]; mbv[h] = mixb[h]; msv[h] = mixs[h]; }
    float rm[NH], tm[NH];
    float rs_[NH] = {0.f,0.f,0.f,0.f}, ts_[NH] = {0.f,0.f,0.f,0.f};
    #pragma unroll
    for (int h = 0; h < NH; ++h) { rm[h] = -1e30f; tm[h] = -1e30f; }
    for (int base = i0; base < i1; base += 64) {
      int i = base + g; bool act = (i < i1);
      int2 sv = act ? cse[i] : make_int2(0, 0);
      int s = sv.x; float len = __int_as_float(sv.y);
      float4 as4 = sr4[s], cs4 = st4[s];
      const float* asp = (const float*)&as4; const float* csp = (const float*)&cs4;
      #pragma unroll
      for (int h = 0; h < NH; ++h) {
        float temp = softplusf(tofnp[h] + rtwv[h] * len);
        float rl = act ? __fdividef(asp[h] - srnp[h] - dofnp[h] * len, temp + 1e-4f) : -1e30f;
        float tl = act ? (csp[h] - stnp[h]) : -1e30f;
        rm[h] = fmaxf(rm[h], rl); tm[h] = fmaxf(tm[h], tl);
      }
    }
    #pragma unroll
    for (int off = 32; off; off >>= 1)
      #pragma unroll
      for (int h = 0; h < NH; ++h) {
        rm[h] = fmaxf(rm[h], __shfl_xor(rm[h], off));
        tm[h] = fmaxf(tm[h], __shfl_xor(tm[h], off));
      }
    for (int base = i0; base < i1; base += 64) {
      int i = base + g; bool act = (i < i1);
      int2 sv = act ? cse[i] : make_int2(0, 0);
      int s = sv.x; float len = __int_as_float(sv.y);
      float4 as4 = sr4[s], cs4 = st4[s];
      const float* asp = (const float*)&as4; const float* csp = (const float*)&cs4;
      #pragma unroll
      for (int h = 0; h < NH; ++h) {
        float temp = softplusf(tofnp[h] + rtwv[h] * len);
        float rl = act ? __fdividef(asp[h] - srnp[h] - dofnp[h] * len, temp + 1e-4f) : -1e30f;
        float tl = act ? (csp[h] - stnp[h]) : -1e30f;
        rs_[h] += act ? fexp(rl - rm[h]) : 0.f;
        ts_[h] += act ? fexp(tl - tm[h]) : 0.f;
      }
    }
    #pragma unroll
    for (int off = 32; off; off >>= 1)
      #pragma unroll
      for (int h = 0; h < NH; ++h) { rs_[h] += __shfl_xor(rs_[h], off); ts_[h] += __shfl_xor(ts_[h], off); }
    #pragma unroll
    for (int h = 0; h < NH; ++h) { rs_[h] = __fdividef(1.f, rs_[h] + 1e-9f); ts_[h] = __fdividef(1.f, ts_[h] + 1e-9f); }
    for (int base = i0; base < i1; base += 64) {
      int i = base + g; bool act = (i < i1);
      int2 sv = act ? cse[i] : make_int2(0, 0);
      int s = sv.x; float len = __int_as_float(sv.y);
      float4 as4 = sr4[s], cs4 = st4[s];
      const float* asp = (const float*)&as4; const float* csp = (const float*)&cs4;
      #pragma unroll
      for (int h = 0; h < NH; ++h) {
        float temp = softplusf(tofnp[h] + rtwv[h] * len);
        float rl = act ? __fdividef(asp[h] - srnp[h] - dofnp[h] * len, temp + 1e-4f) : -1e30f;
        float tl = act ? (csp[h] - stnp[h]) : -1e30f;
        float gg = sigmoidf_(mbv[h] + msv[h] * len);
        float ar = (act ? fexp(rl - rm[h]) : 0.f) * rs_[h];
        float at = (act ? fexp(tl - tm[h]) : 0.f) * ts_[h];
        float ba = gg * ar + (1.f - gg) * at;
        float c1 = ba * gg, c2 = ba * (1.f - gg);
        coef_s[w][g][h] = c1; coef_s[w][g][4 + h] = c2;
        sc1[h] += c1; sc2[h] += c2;
      }
      snd_s[w][g] = s;
      int cnt = min(64, i1 - base);
      int j = 0;
      for (; j + 4 <= cnt; j += 4) {
        uint4 u0 = *(const uint4*)(ptb + ((size_t)snd_s[w][j]     * NF + g) * 8);
        uint4 u1 = *(const uint4*)(ptb + ((size_t)snd_s[w][j + 1] * NF + g) * 8);
        uint4 u2 = *(const uint4*)(ptb + ((size_t)snd_s[w][j + 2] * NF + g) * 8);
        uint4 u3 = *(const uint4*)(ptb + ((size_t)snd_s[w][j + 3] * NF + g) * 8);
        acc0 += dot8(coef_s[w][j],     u0);
        acc1 += dot8(coef_s[w][j + 1], u1);
        acc2 += dot8(coef_s[w][j + 2], u2);
        acc3 += dot8(coef_s[w][j + 3], u3);
      }
      for (; j < cnt; ++j) {
        uint4 u0 = *(const uint4*)(ptb + ((size_t)snd_s[w][j] * NF + g) * 8);
        acc0 += dot8(coef_s[w][j], u0);
      }
    }
  }

  float acc = (acc0 + acc1) + (acc2 + acc3);
  #pragma unroll
  for (int off = 32; off; off >>= 1)
    #pragma unroll
    for (int h = 0; h < NH; ++h) { sc1[h] += __shfl_xor(sc1[h], off); sc2[h] += __shfl_xor(sc2[h], off); }

  {
    uint4 uv = *(const uint4*)(ptb + ((size_t)n * NF + g) * 8);
    acc -= sc1[0] * bflo(uv.x) + sc1[1] * bfhi(uv.x)
         + sc1[2] * bflo(uv.y) + sc1[3] * bfhi(uv.y)
         + sc2[0] * bflo(uv.z) + sc2[1] * bfhi(uv.z)
         + sc2[2] * bflo(uv.w) + sc2[3] * bfhi(uv.w);
  }
  acc *= (1.f / NH);

  am_s[w][g] = acc;   // wave-local LDS; no block barrier needed
  float o = x[(size_t)n * NF + g];
  #pragma unroll 8
  for (int f = 0; f < NF; ++f) o += am_s[w][f] * wout_s[f * NF + g];
  out[(size_t)n * NF + g] = o;
}

extern "C" void kernel_launch(void* const* d_in, const int* in_sizes, int n_in,
                              void* d_out, int out_size, void* d_ws, size_t ws_size,
                              hipStream_t stream) {
  const float* x    = (const float*)d_in[0];
  const int*   ei   = (const int*)d_in[1];
  // d_in[2] = edge_vec, unused by the reference
  const float* elen = (const float*)d_in[3];
  const float* Wp   = (const float*)d_in[4];
  const float* Wr   = (const float*)d_in[5];
  const float* Wt   = (const float*)d_in[6];
  const float* rsc  = (const float*)d_in[7];
  const float* tsc  = (const float*)d_in[8];
  const float* rdls = (const float*)d_in[9];
  const float* rtb  = (const float*)d_in[10];
  const float* rtw  = (const float*)d_in[11];
  const float* mixb = (const float*)d_in[12];
  const float* mixs = (const float*)d_in[13];
  const float* dW1  = (const float*)d_in[14];
  const float* db1  = (const float*)d_in[15];
  const float* dw2  = (const float*)d_in[16];
  const float* db2  = (const float*)d_in[17];
  const float* tW1  = (const float*)d_in[18];
  const float* tb1  = (const float*)d_in[19];
  const float* tw2  = (const float*)d_in[20];
  const float* tb2  = (const float*)d_in[21];
  const float* Wout = (const float*)d_in[22];

  int N = in_sizes[0] / NF;
  int E = in_sizes[3];

  float* p = (float*)d_ws;
  unsigned short* Wpk = (unsigned short*)p; p += 32768;  // 128 frag x 64 lanes x 8 bf16 = 131072 B
  unsigned short* ptb = (unsigned short*)p; p += (size_t)N * NF * 8 / 2;  // [n][g][8] bf16
  float* sr   = p; p += (size_t)N * NH;
  float* st   = p; p += (size_t)N * NH;
  float* doff = p; p += (size_t)N * NH;
  float* toff = p; p += (size_t)N * NH;
  int2* cse   = (int2*)p; p += (size_t)2 * E;  // CSR-ordered {sender, elen}
  int* slotw  = (int*)p; p += E;               // slot-within-receiver per edge
  int* deg    = (int*)p; p += N;
  int* startp = (int*)p; p += N + 1;

  // K0: pack weights + zero deg
  k_pack<<<32, 256, 0, stream>>>(Wp, Wr, Wt, dW1, tW1, Wpk, deg, N);
  // K1: MFMA node pass + fused degree count
  k_projm<<<(N + NT - 1) / NT, 256, 0, stream>>>(x, Wpk, rsc, tsc, db1, dw2, db2,
                                                 tb1, tw2, tb2, rdls, rtb,
                                                 ptb, sr, st, doff, toff,
                                                 ei, deg, slotw, N, E);
  // K2: scan degrees -> CSR starts
  k_scan<<<1, 1024, 0, stream>>>(deg, startp, N);
  // K3: CSR fill (no atomics)
  k_fill<<<(E + 255) / 256, 256, 0, stream>>>(ei, elen, startp, slotw, cse, E);
  // K4: fused logits + softmax + aggregate + output
  k_aggout<<<(N + AW - 1) / AW, 512, 0, stream>>>(startp, cse,
                                                  (const float4*)sr, (const float4*)st,
                                                  (const float4*)doff, (const float4*)toff,
                                                  rtw, mixb, mixs, ptb, x, Wout, (float*)d_out, N);
}

// Round 25
// 108.379 us; speedup vs baseline: 1.4953x; 1.0550x over previous
//
#include <hip/hip_runtime.h>
#include <math.h>

#define NH 4
#define NF 64
#define NM 32
#define NT 16  // nodes per block in k_projm
#define SC 32  // elements per thread in k_scan (supports N <= 32768)
#define AW 8   // waves per block in k_aggout

typedef __attribute__((ext_vector_type(8))) short bf16x8;
typedef __attribute__((ext_vector_type(4))) float f32x4;

// fast transcendentals (hardware v_exp/v_log/v_rcp); absmax margin 0.03 vs 0.105 absorbs ~1e-6
__device__ __forceinline__ float fexp(float v){ return __expf(v); }
__device__ __forceinline__ float softplusf(float v){ return fmaxf(v, 0.f) + __logf(1.f + __expf(-fabsf(v))); }
__device__ __forceinline__ float sigmoidf_(float v){ return __fdividef(1.f, 1.f + __expf(-v)); }
__device__ __forceinline__ unsigned short f2bf(float f) {
  unsigned u = __float_as_uint(f);
  u = u + 0x7FFFu + ((u >> 16) & 1u);   // round-to-nearest-even
  return (unsigned short)(u >> 16);
}
__device__ __forceinline__ float bflo(unsigned u){ return __uint_as_float(u << 16); }
__device__ __forceinline__ float bfhi(unsigned u){ return __uint_as_float(u & 0xFFFF0000u); }

// ---------------- K0: pack weights into MFMA fragments + zero deg ----------------
__global__ void k_pack(const float* __restrict__ Wp, const float* __restrict__ Wr,
                       const float* __restrict__ Wt,
                       const float* __restrict__ dW1, const float* __restrict__ tW1,
                       unsigned short* __restrict__ Wpk, int* __restrict__ z, int nz) {
  int t = blockIdx.x * blockDim.x + threadIdx.x;   // 8192 threads
  for (int i = t; i < nz; i += 8192) z[i] = 0;
  int lane = t & 63;
  int frag = t >> 6;   // 0..127
  if (frag >= 128) return;
  if (frag < 96) {
    int nb = frag & 3, kb = (frag >> 2) & 1, h = (frag >> 3) & 3, q = frag >> 5;
    const float* W = (q == 0 ? Wp : (q == 1 ? Wr : Wt));
    int col = nb * 16 + (lane & 15);
    int krow = kb * 32 + (lane >> 4) * 8;
    #pragma unroll
    for (int j = 0; j < 8; ++j)
      Wpk[((size_t)frag * 64 + lane) * 8 + j] = f2bf(W[(size_t)h * NF * NF + (krow + j) * NF + col]);
  } else {
    int f2 = frag - 96;
    int nb = f2 & 1, kb = (f2 >> 1) & 1, h = (f2 >> 2) & 3, p2 = f2 >> 4;
    const float* W = (p2 == 0 ? dW1 : tW1);
    int col = nb * 16 + (lane & 15);
    int krow = kb * 32 + (lane >> 4) * 8;
    #pragma unroll
    for (int j = 0; j < 8; ++j)
      Wpk[((size_t)frag * 64 + lane) * 8 + j] = f2bf(W[(size_t)h * NF * NM + (krow + j) * NM + col]);
  }
}

// ---------------- K1: MFMA node pass + edge degree count (fused) ----------------
__global__ __launch_bounds__(256)
void k_projm(const float* __restrict__ x, const unsigned short* __restrict__ Wpk,
             const float* __restrict__ rsc, const float* __restrict__ tsc,
             const float* __restrict__ db1, const float* __restrict__ dw2, const float* __restrict__ db2,
             const float* __restrict__ tb1, const float* __restrict__ tw2, const float* __restrict__ tb2,
             const float* __restrict__ rdls, const float* __restrict__ rtb,
             unsigned short* __restrict__ ptb, float* __restrict__ sr, float* __restrict__ st,
             float* __restrict__ doff, float* __restrict__ toff,
             const int* __restrict__ ei, int* __restrict__ deg, int* __restrict__ slotw,
             int N, int E) {
  int n0 = blockIdx.x * NT;
  int tid = threadIdx.x;
  int h = tid >> 6, l = tid & 63;
  int lo = l & 15, hi = l >> 4;
  __shared__ __align__(16) unsigned short eps16[NH][16][72];  // bf16 ep, padded rows
  __shared__ __align__(16) unsigned short pts[NT][NF][8];     // staged rp/tp (16 KB)

  const bf16x8* W8 = (const bf16x8*)Wpk;

  bf16x8 a[2];
  {
    int nr = n0 + lo; if (nr >= N) nr = N - 1;
    const float* xr = x + (size_t)nr * NF + hi * 8;
    #pragma unroll
    for (int kb = 0; kb < 2; ++kb) {
      float4 v0 = *(const float4*)(xr + kb * 32);
      float4 v1 = *(const float4*)(xr + kb * 32 + 4);
      bf16x8 aa;
      aa[0] = (short)f2bf(v0.x); aa[1] = (short)f2bf(v0.y);
      aa[2] = (short)f2bf(v0.z); aa[3] = (short)f2bf(v0.w);
      aa[4] = (short)f2bf(v1.x); aa[5] = (short)f2bf(v1.y);
      aa[6] = (short)f2bf(v1.z); aa[7] = (short)f2bf(v1.w);
      a[kb] = aa;
    }
  }

  float srp[4] = {0.f,0.f,0.f,0.f}, stp[4] = {0.f,0.f,0.f,0.f};
  #pragma unroll
  for (int q = 0; q < 3; ++q) {
    #pragma unroll
    for (int nb = 0; nb < 4; ++nb) {
      f32x4 c = {0.f, 0.f, 0.f, 0.f};
      #pragma unroll
      for (int kb = 0; kb < 2; ++kb) {
        int frag = ((q * 4 + h) * 2 + kb) * 4 + nb;
        c = __builtin_amdgcn_mfma_f32_16x16x32_bf16(a[kb], W8[frag * 64 + l], c, 0, 0, 0);
      }
      int g = nb * 16 + lo;
      if (q == 0) {
        float rs = rsc[h * NF + g], ts = tsc[h * NF + g];
        #pragma unroll
        for (int r = 0; r < 4; ++r) {
          eps16[h][hi * 4 + r][g] = f2bf(c[r]);
          srp[r] += c[r] * rs;
          stp[r] += c[r] * ts;
        }
      } else {
        int row = (q - 1) * NH + h;
        #pragma unroll
        for (int r = 0; r < 4; ++r)
          pts[hi * 4 + r][g][row] = f2bf(c[r]);   // 2-way LDS bank alias: free
      }
    }
  }
  #pragma unroll
  for (int off = 1; off < 16; off <<= 1)
    #pragma unroll
    for (int r = 0; r < 4; ++r) { srp[r] += __shfl_xor(srp[r], off); stp[r] += __shfl_xor(stp[r], off); }
  if (lo == 0) {
    #pragma unroll
    for (int r = 0; r < 4; ++r) {
      int n = n0 + hi * 4 + r;
      if (n < N) { sr[n * NH + h] = srp[r]; st[n * NH + h] = stp[r]; }
    }
  }

  asm volatile("s_waitcnt lgkmcnt(0)" ::: "memory");
  bf16x8 ea[2];
  #pragma unroll
  for (int kb = 0; kb < 2; ++kb)
    ea[kb] = *(const bf16x8*)&eps16[h][lo][kb * 32 + hi * 8];

  float dpp[4] = {0.f,0.f,0.f,0.f}, tpp[4] = {0.f,0.f,0.f,0.f};
  #pragma unroll
  for (int p2 = 0; p2 < 2; ++p2) {
    #pragma unroll
    for (int nb = 0; nb < 2; ++nb) {
      f32x4 c = {0.f, 0.f, 0.f, 0.f};
      #pragma unroll
      for (int kb = 0; kb < 2; ++kb) {
        int frag = 96 + ((p2 * 4 + h) * 2 + kb) * 2 + nb;
        c = __builtin_amdgcn_mfma_f32_16x16x32_bf16(ea[kb], W8[frag * 64 + l], c, 0, 0, 0);
      }
      int m = nb * 16 + lo;
      float b1 = (p2 == 0 ? db1 : tb1)[h * NM + m];
      float w2 = (p2 == 0 ? dw2 : tw2)[h * NM + m];
      #pragma unroll
      for (int r = 0; r < 4; ++r) {
        float av = c[r] + b1;
        float sv = av * sigmoidf_(av) * w2;   // silu * w2
        if (p2 == 0) dpp[r] += sv; else tpp[r] += sv;
      }
    }
  }
  #pragma unroll
  for (int off = 1; off < 16; off <<= 1)
    #pragma unroll
    for (int r = 0; r < 4; ++r) { dpp[r] += __shfl_xor(dpp[r], off); tpp[r] += __shfl_xor(tpp[r], off); }
  if (lo == 0) {
    float dbase = db2[h] + softplusf(rdls[h]);
    float tbase = tb2[h] + rtb[h];
    #pragma unroll
    for (int r = 0; r < 4; ++r) {
      int n = n0 + hi * 4 + r;
      if (n < N) { doff[n * NH + h] = dpp[r] + dbase; toff[n * NH + h] = tpp[r] + tbase; }
    }
  }

  // coalesced ptb flush
  __syncthreads();
  for (int i = tid; i < NT * NF; i += 256) {
    int n = i >> 6, gg = i & 63;
    int gn = n0 + n;
    if (gn < N)
      *(uint4*)(ptb + ((size_t)gn * NF + gg) * 8) = *(const uint4*)&pts[n][gg][0];
  }

  // fused edge degree count (deg zeroed by k_pack, which ran before)
  for (int e = blockIdx.x * 256 + tid; e < E; e += gridDim.x * 256)
    slotw[e] = atomicAdd(&deg[ei[E + e]], 1);
}

// ---------------- K2: exclusive prefix scan (thread-serial + one tree) ----------------
__global__ void k_scan(const int* __restrict__ deg, int* __restrict__ start, int N) {
  __shared__ int sums[1024];
  int tid = threadIdx.x;
  int base = tid * SC;
  int local[SC];
  int s = 0;
  #pragma unroll
  for (int j = 0; j < SC; ++j) {
    int i = base + j;
    int v = (i < N) ? deg[i] : 0;
    local[j] = s;
    s += v;
  }
  sums[tid] = s;
  __syncthreads();
  for (int off = 1; off < 1024; off <<= 1) {
    int t = (tid >= off) ? sums[tid - off] : 0;
    __syncthreads();
    sums[tid] += t;
    __syncthreads();
  }
  int tbase = (tid > 0) ? sums[tid - 1] : 0;
  #pragma unroll
  for (int j = 0; j < SC; ++j) {
    int i = base + j;
    if (i < N) start[i] = tbase + local[j];
  }
  if (tid == 1023) start[N] = sums[1023];
}

// ---------------- K3: CSR fill (no atomics; int2 combined store) ----------------
__global__ void k_fill(const int* __restrict__ ei, const float* __restrict__ elen,
                       const int* __restrict__ start, const int* __restrict__ slotw,
                       int2* __restrict__ cse, int E) {
  int e = blockIdx.x * blockDim.x + threadIdx.x;
  if (e >= E) return;
  int r = ei[E + e];
  int slot = start[r] + slotw[e];
  cse[slot] = make_int2(ei[e], __float_as_int(elen[e]));
}

// ---------------- K4: fused logits + softmax + gather-aggregate + Wout + residual ----------------
__device__ __forceinline__ float dot8(const float* cf, uint4 uv) {
  return cf[0] * bflo(uv.x) + cf[1] * bfhi(uv.x)
       + cf[2] * bflo(uv.y) + cf[3] * bfhi(uv.y)
       + cf[4] * bflo(uv.z) + cf[5] * bfhi(uv.z)
       + cf[6] * bflo(uv.w) + cf[7] * bfhi(uv.w);
}

__global__ __launch_bounds__(512)
void k_aggout(const int* __restrict__ start, const int2* __restrict__ cse,
              const float4* __restrict__ sr4, const float4* __restrict__ st4,
              const float4* __restrict__ doff4, const float4* __restrict__ toff4,
              const float* __restrict__ rtw, const float* __restrict__ mixb, const float* __restrict__ mixs,
              const unsigned short* __restrict__ ptb, const float* __restrict__ x,
              const float* __restrict__ Wout, float* __restrict__ out, int N) {
  __shared__ float wout_s[NF * NF];
  __shared__ float coef_s[AW][64][8];
  __shared__ int   snd_s[AW][64];
  __shared__ float am_s[AW][NF];
  int tid = threadIdx.x;
  {
    const float4* w4 = (const float4*)Wout;
    float4* s4 = (float4*)wout_s;
    for (int i = tid; i < NF * NF / 4; i += 512) s4[i] = w4[i];
  }
  __syncthreads();   // only block-wide barrier; everything after is wave-local
  int w = tid >> 6, g = tid & 63;
  int n = blockIdx.x * AW + w;
  if (n >= N) return;
  int i0 = start[n], i1 = start[n + 1];
  int deg = i1 - i0;

  float sc1[NH] = {0.f,0.f,0.f,0.f}, sc2[NH] = {0.f,0.f,0.f,0.f};
  float acc0 = 0.f, acc1 = 0.f, acc2 = 0.f, acc3 = 0.f;

  if (deg <= 64) {
    // ---------- fast path: lane = (edge, head); up to 4 chunks of 16 edges ----------
    int eL = g >> 2;          // edge within chunk (0..15)
    int hh = g & 3;           // head
    const float* srf = (const float*)sr4;
    const float* stf = (const float*)st4;
    float srn_h = srf[n * NH + hh], stn_h = stf[n * NH + hh];
    float dof_h = ((const float*)doff4)[n * NH + hh];
    float tof_h = ((const float*)toff4)[n * NH + hh];
    float rtw_h = rtw[hh], mb_h = mixb[hh], ms_h = mixs[hh];

    float rl[4], tl[4], gvc[4];
    int   sE[4];
    #pragma unroll
    for (int c = 0; c < 4; ++c) {
      int eidx = c * 16 + eL;
      bool act = eidx < deg;
      int2 sv = act ? cse[i0 + eidx] : make_int2(0, 0);
      sE[c] = sv.x;
      float len = __int_as_float(sv.y);
      float temp = softplusf(tof_h + rtw_h * len);
      float srs = srf[sv.x * NH + hh];
      float sts = stf[sv.x * NH + hh];
      rl[c] = act ? __fdividef(srs - srn_h - dof_h * len, temp + 1e-4f) : -1e30f;
      tl[c] = act ? (sts - stn_h) : -1e30f;
      gvc[c] = sigmoidf_(mb_h + ms_h * len);
    }
    float rmx = fmaxf(fmaxf(rl[0], rl[1]), fmaxf(rl[2], rl[3]));
    float tmx = fmaxf(fmaxf(tl[0], tl[1]), fmaxf(tl[2], tl[3]));
    #pragma unroll
    for (int off = 4; off < 64; off <<= 1) {
      rmx = fmaxf(rmx, __shfl_xor(rmx, off));
      tmx = fmaxf(tmx, __shfl_xor(tmx, off));
    }
    float er[4], et[4], esum = 0.f, tsum = 0.f;
    #pragma unroll
    for (int c = 0; c < 4; ++c) {
      bool act = (c * 16 + eL) < deg;
      er[c] = act ? fexp(rl[c] - rmx) : 0.f;
      et[c] = act ? fexp(tl[c] - tmx) : 0.f;
      esum += er[c]; tsum += et[c];
    }
    #pragma unroll
    for (int off = 4; off < 64; off <<= 1) {
      esum += __shfl_xor(esum, off);
      tsum += __shfl_xor(tsum, off);
    }
    float rinv = __fdividef(1.f, esum + 1e-9f);
    float tinv = __fdividef(1.f, tsum + 1e-9f);
    float sc1o = 0.f, sc2o = 0.f;
    #pragma unroll
    for (int c = 0; c < 4; ++c) {
      float ar = er[c] * rinv, at = et[c] * tinv;
      float gg = gvc[c];
      float ba = gg * ar + (1.f - gg) * at;
      float c1 = ba * gg, c2 = ba * (1.f - gg);
      sc1o += c1; sc2o += c2;
      int e = c * 16 + eL;
      coef_s[w][e][hh] = c1; coef_s[w][e][4 + hh] = c2;
      if (hh == 0) snd_s[w][e] = sE[c];
    }
    #pragma unroll
    for (int h2 = 0; h2 < NH; ++h2) {
      sc1[h2] = (h2 == hh) ? sc1o : 0.f;
      sc2[h2] = (h2 == hh) ? sc2o : 0.f;
    }
    // gather (lane = feature, 4-way ILP — measured best at deg~10)
    int j = 0;
    for (; j + 4 <= deg; j += 4) {
      uint4 u0 = *(const uint4*)(ptb + ((size_t)snd_s[w][j]     * NF + g) * 8);
      uint4 u1 = *(const uint4*)(ptb + ((size_t)snd_s[w][j + 1] * NF + g) * 8);
      uint4 u2 = *(const uint4*)(ptb + ((size_t)snd_s[w][j + 2] * NF + g) * 8);
      uint4 u3 = *(const uint4*)(ptb + ((size_t)snd_s[w][j + 3] * NF + g) * 8);
      acc0 += dot8(coef_s[w][j],     u0);
      acc1 += dot8(coef_s[w][j + 1], u1);
      acc2 += dot8(coef_s[w][j + 2], u2);
      acc3 += dot8(coef_s[w][j + 3], u3);
    }
    for (; j < deg; ++j) {
      uint4 u0 = *(const uint4*)(ptb + ((size_t)snd_s[w][j] * NF + g) * 8);
      acc0 += dot8(coef_s[w][j], u0);
    }
  } else {
    // ---------- slow path (deg > 64): chunked 3 passes, logits recomputed ----------
    float4 srn = sr4[n], stn = st4[n], dofn = doff4[n], tofn = toff4[n];
    const float* srnp = (const float*)&srn; const float* stnp = (const float*)&stn;
    const float* dofnp = (const float*)&dofn; const float* tofnp = (const float*)&tofn;
    float rtwv[NH], mbv[NH], msv[NH];
    #pragma unroll
    for (int h = 0; h < NH; ++h) { rtwv[h] = rtw[h]; mbv[h] = mixb[h]; msv[h] = mixs[h]; }
    float rm[NH], tm[NH];
    float rs_[NH] = {0.f,0.f,0.f,0.f}, ts_[NH] = {0.f,0.f,0.f,0.f};
    #pragma unroll
    for (int h = 0; h < NH; ++h) { rm[h] = -1e30f; tm[h] = -1e30f; }
    for (int base = i0; base < i1; base += 64) {
      int i = base + g; bool act = (i < i1);
      int2 sv = act ? cse[i] : make_int2(0, 0);
      int s = sv.x; float len = __int_as_float(sv.y);
      float4 as4 = sr4[s], cs4 = st4[s];
      const float* asp = (const float*)&as4; const float* csp = (const float*)&cs4;
      #pragma unroll
      for (int h = 0; h < NH; ++h) {
        float temp = softplusf(tofnp[h] + rtwv[h] * len);
        float rl = act ? __fdividef(asp[h] - srnp[h] - dofnp[h] * len, temp + 1e-4f) : -1e30f;
        float tl = act ? (csp[h] - stnp[h]) : -1e30f;
        rm[h] = fmaxf(rm[h], rl); tm[h] = fmaxf(tm[h], tl);
      }
    }
    #pragma unroll
    for (int off = 32; off; off >>= 1)
      #pragma unroll
      for (int h = 0; h < NH; ++h) {
        rm[h] = fmaxf(rm[h], __shfl_xor(rm[h], off));
        tm[h] = fmaxf(tm[h], __shfl_xor(tm[h], off));
      }
    for (int base = i0; base < i1; base += 64) {
      int i = base + g; bool act = (i < i1);
      int2 sv = act ? cse[i] : make_int2(0, 0);
      int s = sv.x; float len = __int_as_float(sv.y);
      float4 as4 = sr4[s], cs4 = st4[s];
      const float* asp = (const float*)&as4; const float* csp = (const float*)&cs4;
      #pragma unroll
      for (int h = 0; h < NH; ++h) {
        float temp = softplusf(tofnp[h] + rtwv[h] * len);
        float rl = act ? __fdividef(asp[h] - srnp[h] - dofnp[h] * len, temp + 1e-4f) : -1e30f;
        float tl = act ? (csp[h] - stnp[h]) : -1e30f;
        rs_[h] += act ? fexp(rl - rm[h]) : 0.f;
        ts_[h] += act ? fexp(tl - tm[h]) : 0.f;
      }
    }
    #pragma unroll
    for (int off = 32; off; off >>= 1)
      #pragma unroll
      for (int h = 0; h < NH; ++h) { rs_[h] += __shfl_xor(rs_[h], off); ts_[h] += __shfl_xor(ts_[h], off); }
    #pragma unroll
    for (int h = 0; h < NH; ++h) { rs_[h] = __fdividef(1.f, rs_[h] + 1e-9f); ts_[h] = __fdividef(1.f, ts_[h] + 1e-9f); }
    for (int base = i0; base < i1; base += 64) {
      int i = base + g; bool act = (i < i1);
      int2 sv = act ? cse[i] : make_int2(0, 0);
      int s = sv.x; float len = __int_as_float(sv.y);
      float4 as4 = sr4[s], cs4 = st4[s];
      const float* asp = (const float*)&as4; const float* csp = (const float*)&cs4;
      #pragma unroll
      for (int h = 0; h < NH; ++h) {
        float temp = softplusf(tofnp[h] + rtwv[h] * len);
        float rl = act ? __fdividef(asp[h] - srnp[h] - dofnp[h] * len, temp + 1e-4f) : -1e30f;
        float tl = act ? (csp[h] - stnp[h]) : -1e30f;
        float gg = sigmoidf_(mbv[h] + msv[h] * len);
        float ar = (act ? fexp(rl - rm[h]) : 0.f) * rs_[h];
        float at = (act ? fexp(tl - tm[h]) : 0.f) * ts_[h];
        float ba = gg * ar + (1.f - gg) * at;
        float c1 = ba * gg, c2 = ba * (1.f - gg);
        coef_s[w][g][h] = c1; coef_s[w][g][4 + h] = c2;
        sc1[h] += c1; sc2[h] += c2;
      }
      snd_s[w][g] = s;
      int cnt = min(64, i1 - base);
      int j = 0;
      for (; j + 4 <= cnt; j += 4) {
        uint4 u0 = *(const uint4*)(ptb + ((size_t)snd_s[w][j]     * NF + g) * 8);
        uint4 u1 = *(const uint4*)(ptb + ((size_t)snd_s[w][j + 1] * NF + g) * 8);
        uint4 u2 = *(const uint4*)(ptb + ((size_t)snd_s[w][j + 2] * NF + g) * 8);
        uint4 u3 = *(const uint4*)(ptb + ((size_t)snd_s[w][j + 3] * NF + g) * 8);
        acc0 += dot8(coef_s[w][j],     u0);
        acc1 += dot8(coef_s[w][j + 1], u1);
        acc2 += dot8(coef_s[w][j + 2], u2);
        acc3 += dot8(coef_s[w][j + 3], u3);
      }
      for (; j < cnt; ++j) {
        uint4 u0 = *(const uint4*)(ptb + ((size_t)snd_s[w][j] * NF + g) * 8);
        acc0 += dot8(coef_s[w][j], u0);
      }
    }
  }

  float acc = (acc0 + acc1) + (acc2 + acc3);
  #pragma unroll
  for (int off = 32; off; off >>= 1)
    #pragma unroll
    for (int h = 0; h < NH; ++h) { sc1[h] += __shfl_xor(sc1[h], off); sc2[h] += __shfl_xor(sc2[h], off); }

  {
    uint4 uv = *(const uint4*)(ptb + ((size_t)n * NF + g) * 8);
    acc -= sc1[0] * bflo(uv.x) + sc1[1] * bfhi(uv.x)
         + sc1[2] * bflo(uv.y) + sc1[3] * bfhi(uv.y)
         + sc2[0] * bflo(uv.z) + sc2[1] * bfhi(uv.z)
         + sc2[2] * bflo(uv.w) + sc2[3] * bfhi(uv.w);
  }
  acc *= (1.f / NH);

  am_s[w][g] = acc;   // wave-local LDS; no block barrier needed
  float o = x[(size_t)n * NF + g];
  #pragma unroll 8
  for (int f = 0; f < NF; ++f) o += am_s[w][f] * wout_s[f * NF + g];
  out[(size_t)n * NF + g] = o;
}

extern "C" void kernel_launch(void* const* d_in, const int* in_sizes, int n_in,
                              void* d_out, int out_size, void* d_ws, size_t ws_size,
                              hipStream_t stream) {
  const float* x    = (const float*)d_in[0];
  const int*   ei   = (const int*)d_in[1];
  // d_in[2] = edge_vec, unused by the reference
  const float* elen = (const float*)d_in[3];
  const float* Wp   = (const float*)d_in[4];
  const float* Wr   = (const float*)d_in[5];
  const float* Wt   = (const float*)d_in[6];
  const float* rsc  = (const float*)d_in[7];
  const float* tsc  = (const float*)d_in[8];
  const float* rdls = (const float*)d_in[9];
  const float* rtb  = (const float*)d_in[10];
  const float* rtw  = (const float*)d_in[11];
  const float* mixb = (const float*)d_in[12];
  const float* mixs = (const float*)d_in[13];
  const float* dW1  = (const float*)d_in[14];
  const float* db1  = (const float*)d_in[15];
  const float* dw2  = (const float*)d_in[16];
  const float* db2  = (const float*)d_in[17];
  const float* tW1  = (const float*)d_in[18];
  const float* tb1  = (const float*)d_in[19];
  const float* tw2  = (const float*)d_in[20];
  const float* tb2  = (const float*)d_in[21];
  const float* Wout = (const float*)d_in[22];

  int N = in_sizes[0] / NF;
  int E = in_sizes[3];

  float* p = (float*)d_ws;
  unsigned short* Wpk = (unsigned short*)p; p += 32768;  // 128 frag x 64 lanes x 8 bf16 = 131072 B
  unsigned short* ptb = (unsigned short*)p; p += (size_t)N * NF * 8 / 2;  // [n][g][8] bf16
  float* sr   = p; p += (size_t)N * NH;
  float* st   = p; p += (size_t)N * NH;
  float* doff = p; p += (size_t)N * NH;
  float* toff = p; p += (size_t)N * NH;
  int2* cse   = (int2*)p; p += (size_t)2 * E;  // CSR-ordered {sender, elen}
  int* slotw  = (int*)p; p += E;               // slot-within-receiver per edge
  int* deg    = (int*)p; p += N;
  int* startp = (int*)p; p += N + 1;

  // K0: pack weights + zero deg
  k_pack<<<32, 256, 0, stream>>>(Wp, Wr, Wt, dW1, tW1, Wpk, deg, N);
  // K1: MFMA node pass + fused degree count
  k_projm<<<(N + NT - 1) / NT, 256, 0, stream>>>(x, Wpk, rsc, tsc, db1, dw2, db2,
                                                 tb1, tw2, tb2, rdls, rtb,
                                                 ptb, sr, st, doff, toff,
                                                 ei, deg, slotw, N, E);
  // K2: scan degrees -> CSR starts
  k_scan<<<1, 1024, 0, stream>>>(deg, startp, N);
  // K3: CSR fill (no atomics)
  k_fill<<<(E + 255) / 256, 256, 0, stream>>>(ei, elen, startp, slotw, cse, E);
  // K4: fused logits + softmax + aggregate + output
  k_aggout<<<(N + AW - 1) / AW, 512, 0, stream>>>(startp, cse,
                                                  (const float4*)sr, (const float4*)st,
                                                  (const float4*)doff, (const float4*)toff,
                                                  rtw, mixb, mixs, ptb, x, Wout, (float*)d_out, N);
}